// Round 1
// baseline (1949.735 us; speedup 1.0000x reference)
//
#include <hip/hip_runtime.h>
#include <hip/hip_bf16.h>

#define BB   128
#define SS   256
#define FIN  40
#define HH   64
#define DD   128
#define NHH  4
#define DHH  32
#define LL   2
#define FFD  2048
#define NEGV (-1e9f)

// ---------------------------------------------------------------- time mask
__global__ __launch_bounds__(256) void tm_kernel(const float* __restrict__ mask,
                                                 float* __restrict__ tm) {
    int i = blockIdx.x * blockDim.x + threadIdx.x;  // B*S
    if (i >= BB * SS) return;
    const float* m = mask + (size_t)i * FIN;
    float s = 0.f;
    for (int f = 0; f < FIN; ++f) s += m[f];
    tm[i] = (s > 0.f) ? 1.f : 0.f;
}

// ------------------------------------------------- xw = concat(x,mask,delta) @ W_ih^T + b_ih
// block: 192 threads (one per output gate col), 16 rows per block
#define XW_RPB 16
__global__ __launch_bounds__(192) void xw_kernel(const float* __restrict__ x,
                                                 const float* __restrict__ mask,
                                                 const float* __restrict__ delta,
                                                 const float* __restrict__ w_ih,
                                                 const float* __restrict__ b_ih,
                                                 float* __restrict__ xw) {
    __shared__ float inp[XW_RPB][120];
    __shared__ float wl[192][21];   // pad 21 -> conflict-free (odd stride)
    int row0 = blockIdx.x * XW_RPB;
    int tid  = threadIdx.x;

    for (int idx = tid; idx < XW_RPB * 120; idx += 192) {
        int r = idx / 120, k = idx % 120;
        int g = row0 + r;
        float v;
        if (k < 40)      v = x[(size_t)g * FIN + k];
        else if (k < 80) v = mask[(size_t)g * FIN + (k - 40)];
        else             v = delta[(size_t)g * FIN + (k - 80)];
        inp[r][k] = v;
    }

    float acc[XW_RPB];
#pragma unroll
    for (int r = 0; r < XW_RPB; ++r) acc[r] = 0.f;

    for (int kt = 0; kt < 6; ++kt) {            // 6 x 20 = 120
        __syncthreads();
        for (int idx = tid; idx < 192 * 20; idx += 192) {
            int r = idx / 20, k = idx % 20;
            wl[r][k] = w_ih[(size_t)r * 120 + kt * 20 + k];
        }
        __syncthreads();
#pragma unroll
        for (int kk = 0; kk < 20; ++kk) {
            float w = wl[tid][kk];
            int kg = kt * 20 + kk;
#pragma unroll
            for (int r = 0; r < XW_RPB; ++r) acc[r] += w * inp[r][kg];  // broadcast
        }
    }
    float bias = b_ih[tid];
    for (int r = 0; r < XW_RPB; ++r)
        xw[(size_t)(row0 + r) * 192 + tid] = acc[r] + bias;
}

// ---------------------------------------------------------------- GRU scan (sequential over S)
// one block per batch row; 192 threads; W_hh row kept in registers
__global__ __launch_bounds__(192) void gru_scan_kernel(const float* __restrict__ w_hh,
                                                       const float* __restrict__ b_hh,
                                                       const float* __restrict__ xw,
                                                       float* __restrict__ hs) {
    __shared__ float h[HH];
    __shared__ float gh[3 * HH];
    __shared__ float xr[3 * HH];
    int b = blockIdx.x;
    int j = threadIdx.x;

    float w[HH];
#pragma unroll
    for (int k = 0; k < HH; ++k) w[k] = w_hh[(size_t)j * HH + k];
    float bh = b_hh[j];
    if (j < HH) h[j] = 0.f;
    __syncthreads();

    const float* xwb = xw + (size_t)b * SS * 192;
    for (int t = 0; t < SS; ++t) {
        float xv = xwb[t * 192 + j];
        float acc = bh;
#pragma unroll
        for (int k = 0; k < HH; k += 4) {
            float4 hv = *(const float4*)&h[k];   // LDS broadcast
            acc += w[k] * hv.x + w[k + 1] * hv.y + w[k + 2] * hv.z + w[k + 3] * hv.w;
        }
        gh[j] = acc;
        xr[j] = xv;
        __syncthreads();
        if (j < HH) {
            float r  = 1.f / (1.f + __expf(-(xr[j] + gh[j])));
            float zg = 1.f / (1.f + __expf(-(xr[64 + j] + gh[64 + j])));
            float n  = tanhf(xr[128 + j] + r * gh[128 + j]);
            float hn = (1.f - zg) * n + zg * h[j];
            h[j] = hn;
            hs[((size_t)b * SS + t) * HH + j] = hn;
        }
        __syncthreads();
    }
}

// ---------------------------------------------------------------- generic fp32 tiled GEMM
// C[M,N] = A[M,K] @ W[N,K]^T + bias  (torch weight layout), optional ReLU
// tile 64x64, BK=16, 256 threads, 4x4 micro-tile. M%64==0, N%64==0, K%16==0.
template <bool RELU>
__global__ __launch_bounds__(256) void gemm_kernel(const float* __restrict__ A,
                                                   const float* __restrict__ W,
                                                   const float* __restrict__ bias,
                                                   float* __restrict__ C,
                                                   int M, int N, int K) {
    __shared__ float As[16][68];
    __shared__ float Ws[16][68];
    int bm = blockIdx.x, bn = blockIdx.y;
    int tid = threadIdx.x;
    int tx = tid % 16, ty = tid / 16;
    int lr = tid / 4, lk = tid % 4;

    const float* Ab = A + ((size_t)bm * 64 + lr) * K + lk * 4;
    const float* Wb = W + ((size_t)bn * 64 + lr) * K + lk * 4;

    float acc[4][4] = {};

    for (int kt = 0; kt < K; kt += 16) {
        float4 av = *(const float4*)(Ab + kt);
        float4 wv = *(const float4*)(Wb + kt);
        __syncthreads();
        As[lk * 4 + 0][lr] = av.x; As[lk * 4 + 1][lr] = av.y;
        As[lk * 4 + 2][lr] = av.z; As[lk * 4 + 3][lr] = av.w;
        Ws[lk * 4 + 0][lr] = wv.x; Ws[lk * 4 + 1][lr] = wv.y;
        Ws[lk * 4 + 2][lr] = wv.z; Ws[lk * 4 + 3][lr] = wv.w;
        __syncthreads();
#pragma unroll
        for (int kk = 0; kk < 16; ++kk) {
            float a[4], w[4];
            *(float4*)a = *(const float4*)&As[kk][ty * 4];
            *(float4*)w = *(const float4*)&Ws[kk][tx * 4];
#pragma unroll
            for (int i = 0; i < 4; ++i)
#pragma unroll
                for (int jj = 0; jj < 4; ++jj)
                    acc[i][jj] = fmaf(a[i], w[jj], acc[i][jj]);
        }
    }

#pragma unroll
    for (int i = 0; i < 4; ++i) {
        int row = bm * 64 + ty * 4 + i;
        int col = bn * 64 + tx * 4;
        float4 o;
        o.x = acc[i][0] + bias[col + 0];
        o.y = acc[i][1] + bias[col + 1];
        o.z = acc[i][2] + bias[col + 2];
        o.w = acc[i][3] + bias[col + 3];
        if (RELU) {
            o.x = fmaxf(o.x, 0.f); o.y = fmaxf(o.y, 0.f);
            o.z = fmaxf(o.z, 0.f); o.w = fmaxf(o.w, 0.f);
        }
        *(float4*)&C[(size_t)row * N + col] = o;
    }
}

// ---------------------------------------------------------------- attention (per b,head; thread = q-row)
__global__ __launch_bounds__(256) void attn_kernel(const float* __restrict__ qkv,
                                                   const float* __restrict__ tm,
                                                   float* __restrict__ attno) {
    int bh = blockIdx.x;
    int b = bh / NHH, hd = bh % NHH;
    int s = threadIdx.x;  // q row, 256 == SS

    __shared__ float Kt[64][DHH];
    __shared__ float Vt[64][DHH];
    __shared__ float tms[64];

    float q[DHH];
    const float* qrow = qkv + ((size_t)b * SS + s) * 384 + hd * DHH;
#pragma unroll
    for (int j = 0; j < DHH; j += 4) {
        float4 v4 = *(const float4*)(qrow + j);
        q[j] = v4.x; q[j + 1] = v4.y; q[j + 2] = v4.z; q[j + 3] = v4.w;
    }
    const float scale = 0.17677669529663687f;  // 1/sqrt(32)
    float denom = 0.f;
    float o[DHH];
#pragma unroll
    for (int j = 0; j < DHH; ++j) o[j] = 0.f;

    for (int kt = 0; kt < SS; kt += 64) {
        __syncthreads();
        for (int idx = s; idx < 512; idx += 256) {
            int r = idx >> 3, c = (idx & 7) * 4;
            const float* base = qkv + ((size_t)b * SS + kt + r) * 384 + hd * DHH;
            *(float4*)&Kt[r][c] = *(const float4*)(base + 128 + c);
            *(float4*)&Vt[r][c] = *(const float4*)(base + 256 + c);
        }
        if (s < 64) tms[s] = tm[b * SS + kt + s];
        __syncthreads();
        for (int k = 0; k < 64; ++k) {
            float acc = 0.f;
#pragma unroll
            for (int j = 0; j < DHH; ++j) acc += q[j] * Kt[k][j];  // broadcast
            float sc = acc * scale + (tms[k] > 0.f ? 0.f : NEGV);
            float e = __expf(sc);   // scores are O(0.3) here; masked -> exp(-1e9)=0
            denom += e;
#pragma unroll
            for (int j = 0; j < DHH; ++j) o[j] += e * Vt[k][j];
        }
    }
    float inv = 1.f / denom;
    float* orow = attno + ((size_t)b * SS + s) * DD + hd * DHH;
#pragma unroll
    for (int j = 0; j < DHH; j += 4) {
        float4 v4 = {o[j] * inv, o[j + 1] * inv, o[j + 2] * inv, o[j + 3] * inv};
        *(float4*)(orow + j) = v4;
    }
}

// ---------------------------------------------------------------- residual + LayerNorm (wave per row)
__global__ __launch_bounds__(256) void resln_kernel(float* __restrict__ z,
                                                    const float* __restrict__ addv,
                                                    const float* __restrict__ sg,
                                                    const float* __restrict__ bg) {
    int row  = blockIdx.x * 4 + (threadIdx.x >> 6);
    int lane = threadIdx.x & 63;
    float2 zv = *(const float2*)&z[(size_t)row * DD + lane * 2];
    float2 av = *(const float2*)&addv[(size_t)row * DD + lane * 2];
    float x0 = zv.x + av.x, x1 = zv.y + av.y;
    float sum = x0 + x1;
#pragma unroll
    for (int off = 32; off; off >>= 1) sum += __shfl_xor(sum, off);
    float mean = sum * (1.f / 128.f);
    float d0 = x0 - mean, d1 = x1 - mean;
    float vs = d0 * d0 + d1 * d1;
#pragma unroll
    for (int off = 32; off; off >>= 1) vs += __shfl_xor(vs, off);
    float rstd = rsqrtf(vs * (1.f / 128.f) + 1e-5f);
    float2 sv = *(const float2*)&sg[lane * 2];
    float2 bv = *(const float2*)&bg[lane * 2];
    float2 out = {d0 * rstd * sv.x + bv.x, d1 * rstd * sv.y + bv.y};
    *(float2*)&z[(size_t)row * DD + lane * 2] = out;
}

// ---------------------------------------------------------------- score = z @ score_w^T + b (masked)
__global__ __launch_bounds__(256) void score_kernel(const float* __restrict__ z,
                                                    const float* __restrict__ score_w,
                                                    const float* __restrict__ score_b,
                                                    const float* __restrict__ tm,
                                                    float* __restrict__ scores) {
    int row = blockIdx.x * 64 + (threadIdx.x >> 2);
    int c = threadIdx.x & 3;
    const float* zr = z + (size_t)row * DD + c * 32;
    const float* wr = score_w + c * 32;
    float acc = 0.f;
#pragma unroll
    for (int j = 0; j < 32; j += 4) {
        float4 a = *(const float4*)(zr + j), w = *(const float4*)(wr + j);
        acc += a.x * w.x + a.y * w.y + a.z * w.z + a.w * w.w;
    }
    acc += __shfl_xor(acc, 1);
    acc += __shfl_xor(acc, 2);
    if (c == 0) {
        float sc = acc + score_b[0];
        scores[row] = (tm[row] > 0.f) ? sc : NEGV;
    }
}

// ---------------------------------------------------------------- softmax over S + weighted pool
__global__ __launch_bounds__(256) void pool_kernel(const float* __restrict__ z,
                                                   const float* __restrict__ scores,
                                                   float* __restrict__ pooled) {
    int b = blockIdx.x;
    int tid = threadIdx.x;
    __shared__ float al[SS];
    __shared__ float red[8];
    __shared__ float pp[2][128];

    float sc = scores[b * SS + tid];
    float m = sc;
#pragma unroll
    for (int off = 32; off; off >>= 1) m = fmaxf(m, __shfl_xor(m, off));
    if ((tid & 63) == 0) red[tid >> 6] = m;
    __syncthreads();
    m = fmaxf(fmaxf(red[0], red[1]), fmaxf(red[2], red[3]));
    float e = __expf(sc - m);
    float ssum = e;
#pragma unroll
    for (int off = 32; off; off >>= 1) ssum += __shfl_xor(ssum, off);
    if ((tid & 63) == 0) red[4 + (tid >> 6)] = ssum;
    __syncthreads();
    ssum = red[4] + red[5] + red[6] + red[7];
    al[tid] = e / ssum;
    __syncthreads();

    int d = tid & 127, half = tid >> 7;
    float acc = 0.f;
    for (int t = half; t < SS; t += 2) acc += al[t] * z[((size_t)b * SS + t) * DD + d];
    pp[half][d] = acc;
    __syncthreads();
    if (tid < 128) pooled[b * 128 + tid] = pp[0][tid] + pp[1][tid];
}

// ---------------------------------------------------------------- routed heads
__global__ __launch_bounds__(128) void head_kernel(const float* __restrict__ pooled,
                                                   const float* __restrict__ reg_w,
                                                   const float* __restrict__ reg_b,
                                                   const float* __restrict__ bin_w,
                                                   const float* __restrict__ bin_b,
                                                   const int* __restrict__ wid,
                                                   float* __restrict__ out) {
    int b = blockIdx.x, tid = threadIdx.x;
    __shared__ float p[128];
    p[tid] = pooled[b * 128 + tid];
    __syncthreads();
    if (tid < 9) {
        int w = wid[b];
        const float* wrow;
        float bias;
        if (tid < 8) { wrow = reg_w + ((size_t)w * 8 + tid) * 128; bias = reg_b[w * 8 + tid]; }
        else         { wrow = bin_w + (size_t)w * 128;             bias = bin_b[w]; }
        float acc = bias;
        for (int k = 0; k < 128; ++k) acc += wrow[k] * p[k];
        if (tid < 8) out[b * 8 + tid] = acc;
        else         out[1024 + b] = acc;
    }
}

// ================================================================ host
extern "C" void kernel_launch(void* const* d_in, const int* in_sizes, int n_in,
                              void* d_out, int out_size, void* d_ws, size_t ws_size,
                              hipStream_t stream) {
    const float* x         = (const float*)d_in[0];
    const float* mask      = (const float*)d_in[1];
    const float* delta     = (const float*)d_in[2];
    const float* gru_w_ih  = (const float*)d_in[3];
    const float* gru_w_hh  = (const float*)d_in[4];
    const float* gru_b_ih  = (const float*)d_in[5];
    const float* gru_b_hh  = (const float*)d_in[6];
    const float* dm_w      = (const float*)d_in[7];
    const float* dm_b      = (const float*)d_in[8];
    const float* in_proj_w = (const float*)d_in[9];
    const float* in_proj_b = (const float*)d_in[10];
    const float* out_proj_w= (const float*)d_in[11];
    const float* out_proj_b= (const float*)d_in[12];
    const float* lin1_w    = (const float*)d_in[13];
    const float* lin1_b    = (const float*)d_in[14];
    const float* lin2_w    = (const float*)d_in[15];
    const float* lin2_b    = (const float*)d_in[16];
    const float* ln1_s     = (const float*)d_in[17];
    const float* ln1_bb    = (const float*)d_in[18];
    const float* ln2_s     = (const float*)d_in[19];
    const float* ln2_bb    = (const float*)d_in[20];
    const float* score_w   = (const float*)d_in[21];
    const float* score_b   = (const float*)d_in[22];
    const float* reg_w     = (const float*)d_in[23];
    const float* reg_b     = (const float*)d_in[24];
    const float* bin_w     = (const float*)d_in[25];
    const float* bin_b     = (const float*)d_in[26];
    const int*   window_id = (const int*)d_in[27];
    float* out = (float*)d_out;

    // ws layout (floats), region A reused across phases:
    //   [0 .. 16.78M): GRU: xw(6.29M)+hs(2.10M) | attn: qkv(12.58M)+attno(4.19M) | FF: ffbuf(16.78M)
    float* ws    = (float*)d_ws;
    float* xw    = ws;                       // 6,291,456
    float* hs    = ws + 6291456;             // 2,097,152
    float* qkv   = ws;                       // 12,582,912 (after GRU phase)
    float* attno = ws + 12582912;            // 4,194,304
    float* ffbuf = ws;                       // 16,777,216 (8192 x 2048 chunk)
    float* proj  = ws + 16777216;            // 4,194,304
    float* z     = ws + 20971520;            // 4,194,304
    float* tm    = ws + 25165824;            // 32,768
    float* scores= ws + 25198592;            // 32,768
    float* pooled= ws + 25231360;            // 16,384
    // total ~101 MB

    tm_kernel<<<(BB * SS + 255) / 256, 256, 0, stream>>>(mask, tm);
    xw_kernel<<<BB * SS / XW_RPB, 192, 0, stream>>>(x, mask, delta, gru_w_ih, gru_b_ih, xw);
    gru_scan_kernel<<<BB, 192, 0, stream>>>(gru_w_hh, gru_b_hh, xw, hs);
    // z = hs @ dm_w^T + dm_b   (M=32768, N=128, K=64)
    gemm_kernel<false><<<dim3(512, 2), 256, 0, stream>>>(hs, dm_w, dm_b, z, 32768, 128, 64);

    for (int l = 0; l < LL; ++l) {
        // qkv
        gemm_kernel<false><<<dim3(512, 6), 256, 0, stream>>>(
            z, in_proj_w + (size_t)l * 384 * 128, in_proj_b + l * 384, qkv, 32768, 384, 128);
        attn_kernel<<<BB * NHH, 256, 0, stream>>>(qkv, tm, attno);
        gemm_kernel<false><<<dim3(512, 2), 256, 0, stream>>>(
            attno, out_proj_w + (size_t)l * 128 * 128, out_proj_b + l * 128, proj, 32768, 128, 128);
        resln_kernel<<<BB * SS / 4, 256, 0, stream>>>(z, proj, ln1_s + l * 128, ln1_bb + l * 128);
        // FF in 4 chunks of 8192 rows (ffbuf reuse)
        for (int c = 0; c < 4; ++c) {
            gemm_kernel<true><<<dim3(128, 32), 256, 0, stream>>>(
                z + (size_t)c * 8192 * 128, lin1_w + (size_t)l * 2048 * 128, lin1_b + l * 2048,
                ffbuf, 8192, 2048, 128);
            gemm_kernel<false><<<dim3(128, 2), 256, 0, stream>>>(
                ffbuf, lin2_w + (size_t)l * 128 * 2048, lin2_b + l * 128,
                proj + (size_t)c * 8192 * 128, 8192, 128, 2048);
        }
        resln_kernel<<<BB * SS / 4, 256, 0, stream>>>(z, proj, ln2_s + l * 128, ln2_bb + l * 128);
    }

    score_kernel<<<BB * SS / 64, 256, 0, stream>>>(z, score_w, score_b, tm, scores);
    pool_kernel<<<BB, 256, 0, stream>>>(z, scores, pooled);
    head_kernel<<<BB, 128, 0, stream>>>(pooled, reg_w, reg_b, bin_w, bin_b, window_id, out);
}

// Round 2
// 801.909 us; speedup vs baseline: 2.4314x; 2.4314x over previous
//
#include <hip/hip_runtime.h>

typedef __attribute__((ext_vector_type(8))) short short8;
typedef __attribute__((ext_vector_type(4))) float f32x4;
typedef unsigned short u16;

#define BB   128
#define SS   256
#define FIN  40
#define HH   64
#define DD   128
#define NHH  4
#define LL   2
#define NEGV (-1e9f)

__device__ __forceinline__ u16 f2b(float f) {
    unsigned u = __float_as_uint(f);
    return (u16)((u + 0x7FFFu + ((u >> 16) & 1u)) >> 16);
}
__device__ __forceinline__ float b2f(u16 u) {
    return __uint_as_float(((unsigned)u) << 16);
}

// ---------------------------------------------------------------- fp32 -> bf16 convert
__global__ __launch_bounds__(256) void cvt_f2b_kernel(const float* __restrict__ s,
                                                      u16* __restrict__ d, int n) {
    int i = (blockIdx.x * 256 + threadIdx.x) * 8;
    if (i >= n) return;
    float4 a = *(const float4*)&s[i];
    float4 b = *(const float4*)&s[i + 4];
    short8 o;
    o[0] = (short)f2b(a.x); o[1] = (short)f2b(a.y); o[2] = (short)f2b(a.z); o[3] = (short)f2b(a.w);
    o[4] = (short)f2b(b.x); o[5] = (short)f2b(b.y); o[6] = (short)f2b(b.z); o[7] = (short)f2b(b.w);
    *(short8*)&d[i] = o;
}

// ---------------------------------------------------------------- time mask
__global__ __launch_bounds__(256) void tm_kernel(const float* __restrict__ mask,
                                                 float* __restrict__ tm) {
    int i = blockIdx.x * blockDim.x + threadIdx.x;
    if (i >= BB * SS) return;
    const float* m = mask + (size_t)i * FIN;
    float s = 0.f;
    for (int f = 0; f < FIN; ++f) s += m[f];
    tm[i] = (s > 0.f) ? 1.f : 0.f;
}

// ------------------------------------------------- xw = concat(x,mask,delta) @ W_ih^T + b_ih
#define XW_RPB 16
__global__ __launch_bounds__(192) void xw_kernel(const float* __restrict__ x,
                                                 const float* __restrict__ mask,
                                                 const float* __restrict__ delta,
                                                 const float* __restrict__ w_ih,
                                                 const float* __restrict__ b_ih,
                                                 float* __restrict__ xw) {
    __shared__ float inp[XW_RPB][120];
    __shared__ float wl[192][21];
    int row0 = blockIdx.x * XW_RPB;
    int tid  = threadIdx.x;

    for (int idx = tid; idx < XW_RPB * 120; idx += 192) {
        int r = idx / 120, k = idx % 120;
        int g = row0 + r;
        float v;
        if (k < 40)      v = x[(size_t)g * FIN + k];
        else if (k < 80) v = mask[(size_t)g * FIN + (k - 40)];
        else             v = delta[(size_t)g * FIN + (k - 80)];
        inp[r][k] = v;
    }

    float acc[XW_RPB];
#pragma unroll
    for (int r = 0; r < XW_RPB; ++r) acc[r] = 0.f;

    for (int kt = 0; kt < 6; ++kt) {
        __syncthreads();
        for (int idx = tid; idx < 192 * 20; idx += 192) {
            int r = idx / 20, k = idx % 20;
            wl[r][k] = w_ih[(size_t)r * 120 + kt * 20 + k];
        }
        __syncthreads();
#pragma unroll
        for (int kk = 0; kk < 20; ++kk) {
            float w = wl[tid][kk];
            int kg = kt * 20 + kk;
#pragma unroll
            for (int r = 0; r < XW_RPB; ++r) acc[r] += w * inp[r][kg];
        }
    }
    float bias = b_ih[tid];
    for (int r = 0; r < XW_RPB; ++r)
        xw[(size_t)(row0 + r) * 192 + tid] = acc[r] + bias;
}

// ---------------------------------------------------------------- GRU scan: 1 wave/batch-row
// lane j owns h[j] and all 3 gate rows (192 weight VGPRs); xw prefetched one step ahead
__global__ __launch_bounds__(64, 1) void gru_scan_kernel(const float* __restrict__ w_hh,
                                                         const float* __restrict__ b_hh,
                                                         const float* __restrict__ xw,
                                                         u16* __restrict__ hsb) {
    __shared__ float h[HH];
    int b = blockIdx.x, j = threadIdx.x;

    float wr[HH], wz[HH], wn[HH];
#pragma unroll
    for (int k = 0; k < HH; k += 4) {
        *(float4*)&wr[k] = *(const float4*)&w_hh[(size_t)j * HH + k];
        *(float4*)&wz[k] = *(const float4*)&w_hh[(size_t)(64 + j) * HH + k];
        *(float4*)&wn[k] = *(const float4*)&w_hh[(size_t)(128 + j) * HH + k];
    }
    float br = b_hh[j], bz = b_hh[64 + j], bn = b_hh[128 + j];
    h[j] = 0.f;
    float hj = 0.f;
    const float* xwb = xw + (size_t)b * SS * 192;
    float xr = xwb[j], xz = xwb[64 + j], xn = xwb[128 + j];
    __syncthreads();

    for (int t = 0; t < SS; ++t) {
        int tn = (t + 1 < SS) ? t + 1 : t;           // prefetch next step (hides HBM latency)
        float pxr = xwb[(size_t)tn * 192 + j];
        float pxz = xwb[(size_t)tn * 192 + 64 + j];
        float pxn = xwb[(size_t)tn * 192 + 128 + j];

        float ar = br, az = bz, an = bn;
#pragma unroll
        for (int k = 0; k < HH; k += 4) {
            float4 hv = *(const float4*)&h[k];       // LDS broadcast
            ar += wr[k]*hv.x + wr[k+1]*hv.y + wr[k+2]*hv.z + wr[k+3]*hv.w;
            az += wz[k]*hv.x + wz[k+1]*hv.y + wz[k+2]*hv.z + wz[k+3]*hv.w;
            an += wn[k]*hv.x + wn[k+1]*hv.y + wn[k+2]*hv.z + wn[k+3]*hv.w;
        }
        float r  = 1.f / (1.f + __expf(-(xr + ar)));
        float zg = 1.f / (1.f + __expf(-(xz + az)));
        float nx = xn + r * an;
        float n  = 2.f / (1.f + __expf(-2.f * nx)) - 1.f;   // tanh
        hj = (1.f - zg) * n + zg * hj;
        __syncthreads();                              // all lanes done reading old h
        h[j] = hj;
        hsb[((size_t)b * SS + t) * HH + j] = f2b(hj);
        __syncthreads();                              // new h visible
        xr = pxr; xz = pxz; xn = pxn;
    }
}

// ---------------------------------------------------------------- bf16 MFMA GEMM (m97 structure)
// C[M,N] = A[M,K] @ W[N,K]^T + bias ; A,W bf16 row-major K-contiguous
// 128x128 tile, 4 waves, BK=32, global_load_lds(16B), single LDS buffer + 2 barriers
__device__ __forceinline__ void gl_lds16(const void* g, void* s) {
    __builtin_amdgcn_global_load_lds(
        (const __attribute__((address_space(1))) void*)g,
        (__attribute__((address_space(3))) void*)s, 16, 0, 0);
}

template <int OUTMODE, bool RELU>   // OUTMODE bit0: fp32 C, bit1: bf16 Cb
__global__ __launch_bounds__(256) void mfma_gemm(const u16* __restrict__ A,
                                                 const u16* __restrict__ W,
                                                 const float* __restrict__ bias,
                                                 float* __restrict__ C,
                                                 u16* __restrict__ Cb,
                                                 int M, int N, int K) {
    __shared__ __align__(16) u16 Al[128 * 32];
    __shared__ __align__(16) u16 Bl[128 * 32];
    int bm = blockIdx.x, bn = blockIdx.y;
    int tid = threadIdx.x;
    int w = tid >> 6, lane = tid & 63;
    int wrow = (w >> 1) * 64, wcol = (w & 1) * 64;
    int fr = lane & 15, fk = (lane >> 4) * 8;
    int srow = lane >> 2;            // row within 16-row staging chunk
    int scol = (lane & 3) * 8;       // elem col within BK=32

    const u16* Ag = A + ((size_t)bm * 128) * K + scol;
    const u16* Wg = W + ((size_t)bn * 128) * K + scol;

    f32x4 acc[4][4];
#pragma unroll
    for (int i = 0; i < 4; ++i)
#pragma unroll
        for (int jj = 0; jj < 4; ++jj) acc[i][jj] = (f32x4){0.f, 0.f, 0.f, 0.f};

    for (int kt = 0; kt < K; kt += 32) {
        __syncthreads();   // previous iter's ds_reads done before overwrite
#pragma unroll
        for (int i = 0; i < 2; ++i) {
            int c = w + i * 4;                 // chunk 0..7, wave-uniform
            int row = c * 16 + srow;
            gl_lds16(Ag + (size_t)row * K + kt, &Al[c * 512]);
            gl_lds16(Wg + (size_t)row * K + kt, &Bl[c * 512]);
        }
        __syncthreads();   // compiler drains vmcnt(0) here
        short8 a[4], bq[4];
#pragma unroll
        for (int m = 0; m < 4; ++m)
            a[m] = *(const short8*)&Al[(wrow + m * 16 + fr) * 32 + fk];
#pragma unroll
        for (int n = 0; n < 4; ++n)
            bq[n] = *(const short8*)&Bl[(wcol + n * 16 + fr) * 32 + fk];
#pragma unroll
        for (int m = 0; m < 4; ++m)
#pragma unroll
            for (int n = 0; n < 4; ++n)
                acc[m][n] = __builtin_amdgcn_mfma_f32_16x16x32_bf16(a[m], bq[n], acc[m][n], 0, 0, 0);
    }

    // epilogue: C/D layout col=lane&15, row=(lane>>4)*4+j  (m89-verified)
    float bv[4];
#pragma unroll
    for (int n = 0; n < 4; ++n) bv[n] = bias[bn * 128 + wcol + n * 16 + (lane & 15)];
#pragma unroll
    for (int m = 0; m < 4; ++m) {
#pragma unroll
        for (int j = 0; j < 4; ++j) {
            int row = bm * 128 + wrow + m * 16 + (lane >> 4) * 4 + j;
#pragma unroll
            for (int n = 0; n < 4; ++n) {
                int col = bn * 128 + wcol + n * 16 + (lane & 15);
                float v = acc[m][n][j] + bv[n];
                if (RELU) v = fmaxf(v, 0.f);
                if (OUTMODE & 1) C[(size_t)row * N + col] = v;
                if (OUTMODE & 2) Cb[(size_t)row * N + col] = f2b(v);
            }
        }
    }
}

// ---------------------------------------------------------------- attention (bf16 qkv in, bf16 out)
__global__ __launch_bounds__(256) void attn_kernel(const u16* __restrict__ qkv,
                                                   const float* __restrict__ tm,
                                                   u16* __restrict__ attno) {
    int bh = blockIdx.x;
    int b = bh / NHH, hd = bh % NHH;
    int s = threadIdx.x;

    __shared__ float Kt[64][32];
    __shared__ float Vt[64][32];
    __shared__ float tms[64];

    float q[32];
    const u16* qrow = qkv + ((size_t)b * SS + s) * 384 + hd * 32;
#pragma unroll
    for (int j = 0; j < 32; j += 8) {
        short8 v = *(const short8*)&qrow[j];
#pragma unroll
        for (int jj = 0; jj < 8; ++jj) q[j + jj] = b2f((u16)v[jj]);
    }
    const float scale = 0.17677669529663687f;  // 1/sqrt(32)
    float denom = 0.f;
    float o[32];
#pragma unroll
    for (int j = 0; j < 32; ++j) o[j] = 0.f;

    for (int kt = 0; kt < SS; kt += 64) {
        __syncthreads();
        {
            int r = s >> 2, c = (s & 3) * 8;
            const u16* kb = qkv + ((size_t)b * SS + kt + r) * 384 + 128 + hd * 32 + c;
            const u16* vb = qkv + ((size_t)b * SS + kt + r) * 384 + 256 + hd * 32 + c;
            short8 kv = *(const short8*)kb;
            short8 vv = *(const short8*)vb;
#pragma unroll
            for (int jj = 0; jj < 8; ++jj) {
                Kt[r][c + jj] = b2f((u16)kv[jj]);
                Vt[r][c + jj] = b2f((u16)vv[jj]);
            }
        }
        if (s < 64) tms[s] = tm[b * SS + kt + s];
        __syncthreads();
        for (int k = 0; k < 64; ++k) {
            float acc = 0.f;
#pragma unroll
            for (int j = 0; j < 32; ++j) acc += q[j] * Kt[k][j];
            float sc = acc * scale + (tms[k] > 0.f ? 0.f : NEGV);
            float e = __expf(sc);
            denom += e;
#pragma unroll
            for (int j = 0; j < 32; ++j) o[j] += e * Vt[k][j];
        }
    }
    float inv = 1.f / denom;
    u16* orow = attno + ((size_t)b * SS + s) * DD + hd * 32;
#pragma unroll
    for (int j = 0; j < 32; j += 8) {
        short8 ov;
#pragma unroll
        for (int jj = 0; jj < 8; ++jj) ov[jj] = (short)f2b(o[j + jj] * inv);
        *(short8*)&orow[j] = ov;
    }
}

// ---------------------------------------------------------------- residual + LN (+ bf16 copy)
__global__ __launch_bounds__(256) void resln_kernel(float* __restrict__ z,
                                                    const float* __restrict__ addv,
                                                    const float* __restrict__ sg,
                                                    const float* __restrict__ bg,
                                                    u16* __restrict__ zb) {
    int row  = blockIdx.x * 4 + (threadIdx.x >> 6);
    int lane = threadIdx.x & 63;
    float2 zv = *(const float2*)&z[(size_t)row * DD + lane * 2];
    float2 av = *(const float2*)&addv[(size_t)row * DD + lane * 2];
    float x0 = zv.x + av.x, x1 = zv.y + av.y;
    float sum = x0 + x1;
#pragma unroll
    for (int off = 32; off; off >>= 1) sum += __shfl_xor(sum, off);
    float mean = sum * (1.f / 128.f);
    float d0 = x0 - mean, d1 = x1 - mean;
    float vs = d0 * d0 + d1 * d1;
#pragma unroll
    for (int off = 32; off; off >>= 1) vs += __shfl_xor(vs, off);
    float rstd = rsqrtf(vs * (1.f / 128.f) + 1e-5f);
    float2 sv = *(const float2*)&sg[lane * 2];
    float2 bv = *(const float2*)&bg[lane * 2];
    float o0 = d0 * rstd * sv.x + bv.x;
    float o1 = d1 * rstd * sv.y + bv.y;
    *(float2*)&z[(size_t)row * DD + lane * 2] = (float2){o0, o1};
    u16 b0 = f2b(o0), b1 = f2b(o1);
    unsigned packed = (unsigned)b0 | ((unsigned)b1 << 16);
    *(unsigned*)&zb[(size_t)row * DD + lane * 2] = packed;
}

// ---------------------------------------------------------------- score = z @ score_w^T + b (masked)
__global__ __launch_bounds__(256) void score_kernel(const float* __restrict__ z,
                                                    const float* __restrict__ score_w,
                                                    const float* __restrict__ score_b,
                                                    const float* __restrict__ tm,
                                                    float* __restrict__ scores) {
    int row = blockIdx.x * 64 + (threadIdx.x >> 2);
    int c = threadIdx.x & 3;
    const float* zr = z + (size_t)row * DD + c * 32;
    const float* wr = score_w + c * 32;
    float acc = 0.f;
#pragma unroll
    for (int j = 0; j < 32; j += 4) {
        float4 a = *(const float4*)(zr + j), w = *(const float4*)(wr + j);
        acc += a.x * w.x + a.y * w.y + a.z * w.z + a.w * w.w;
    }
    acc += __shfl_xor(acc, 1);
    acc += __shfl_xor(acc, 2);
    if (c == 0) {
        float sc = acc + score_b[0];
        scores[row] = (tm[row] > 0.f) ? sc : NEGV;
    }
}

// ---------------------------------------------------------------- softmax over S + weighted pool
__global__ __launch_bounds__(256) void pool_kernel(const float* __restrict__ z,
                                                   const float* __restrict__ scores,
                                                   float* __restrict__ pooled) {
    int b = blockIdx.x;
    int tid = threadIdx.x;
    __shared__ float al[SS];
    __shared__ float red[8];
    __shared__ float pp[2][128];

    float sc = scores[b * SS + tid];
    float m = sc;
#pragma unroll
    for (int off = 32; off; off >>= 1) m = fmaxf(m, __shfl_xor(m, off));
    if ((tid & 63) == 0) red[tid >> 6] = m;
    __syncthreads();
    m = fmaxf(fmaxf(red[0], red[1]), fmaxf(red[2], red[3]));
    float e = __expf(sc - m);
    float ssum = e;
#pragma unroll
    for (int off = 32; off; off >>= 1) ssum += __shfl_xor(ssum, off);
    if ((tid & 63) == 0) red[4 + (tid >> 6)] = ssum;
    __syncthreads();
    ssum = red[4] + red[5] + red[6] + red[7];
    al[tid] = e / ssum;
    __syncthreads();

    int d = tid & 127, half = tid >> 7;
    float acc = 0.f;
    for (int t = half; t < SS; t += 2) acc += al[t] * z[((size_t)b * SS + t) * DD + d];
    pp[half][d] = acc;
    __syncthreads();
    if (tid < 128) pooled[b * 128 + tid] = pp[0][tid] + pp[1][tid];
}

// ---------------------------------------------------------------- routed heads
__global__ __launch_bounds__(128) void head_kernel(const float* __restrict__ pooled,
                                                   const float* __restrict__ reg_w,
                                                   const float* __restrict__ reg_b,
                                                   const float* __restrict__ bin_w,
                                                   const float* __restrict__ bin_b,
                                                   const int* __restrict__ wid,
                                                   float* __restrict__ out) {
    int b = blockIdx.x, tid = threadIdx.x;
    __shared__ float p[128];
    p[tid] = pooled[b * 128 + tid];
    __syncthreads();
    if (tid < 9) {
        int w = wid[b];
        const float* wrow;
        float bias;
        if (tid < 8) { wrow = reg_w + ((size_t)w * 8 + tid) * 128; bias = reg_b[w * 8 + tid]; }
        else         { wrow = bin_w + (size_t)w * 128;             bias = bin_b[w]; }
        float acc = bias;
        for (int k = 0; k < 128; ++k) acc += wrow[k] * p[k];
        if (tid < 8) out[b * 8 + tid] = acc;
        else         out[1024 + b] = acc;
    }
}

// ================================================================ host
extern "C" void kernel_launch(void* const* d_in, const int* in_sizes, int n_in,
                              void* d_out, int out_size, void* d_ws, size_t ws_size,
                              hipStream_t stream) {
    const float* x         = (const float*)d_in[0];
    const float* mask      = (const float*)d_in[1];
    const float* delta     = (const float*)d_in[2];
    const float* gru_w_ih  = (const float*)d_in[3];
    const float* gru_w_hh  = (const float*)d_in[4];
    const float* gru_b_ih  = (const float*)d_in[5];
    const float* gru_b_hh  = (const float*)d_in[6];
    const float* dm_w      = (const float*)d_in[7];
    const float* dm_b      = (const float*)d_in[8];
    const float* in_proj_w = (const float*)d_in[9];
    const float* in_proj_b = (const float*)d_in[10];
    const float* out_proj_w= (const float*)d_in[11];
    const float* out_proj_b= (const float*)d_in[12];
    const float* lin1_w    = (const float*)d_in[13];
    const float* lin1_b    = (const float*)d_in[14];
    const float* lin2_w    = (const float*)d_in[15];
    const float* lin2_b    = (const float*)d_in[16];
    const float* ln1_s     = (const float*)d_in[17];
    const float* ln1_bb    = (const float*)d_in[18];
    const float* ln2_s     = (const float*)d_in[19];
    const float* ln2_bb    = (const float*)d_in[20];
    const float* score_w   = (const float*)d_in[21];
    const float* score_b   = (const float*)d_in[22];
    const float* reg_w     = (const float*)d_in[23];
    const float* reg_b     = (const float*)d_in[24];
    const float* bin_w     = (const float*)d_in[25];
    const float* bin_b     = (const float*)d_in[26];
    const int*   window_id = (const int*)d_in[27];
    float* out = (float*)d_out;

    // ws layout (bytes):
    char* w8 = (char*)d_ws;
    float* z      = (float*)(w8 + 0);            // 16,777,216
    u16*   zb     = (u16*)  (w8 + 16777216);     //  8,388,608
    float* proj   = (float*)(w8 + 25165824);     // 16,777,216
    u16*   hsb    = (u16*)  (w8 + 41943040);     //  4,194,304
    u16*   wb_dm  = (u16*)  (w8 + 46137344);     //     16,384
    u16*   wb_ip  = (u16*)  (w8 + 46153728);     //    196,608
    u16*   wb_op  = (u16*)  (w8 + 46350336);     //     65,536
    u16*   wb_l1  = (u16*)  (w8 + 46415872);     //  1,048,576
    u16*   wb_l2  = (u16*)  (w8 + 47464448);     //  1,048,576
    float* tm     = (float*)(w8 + 48513024);     //    131,072
    float* scores = (float*)(w8 + 48644096);     //    131,072
    float* pooled = (float*)(w8 + 48775168);     //     65,536
    float* xw     = (float*)(w8 + 48840704);     // 25,165,824 (R0: xw fp32 | qkvb bf16)
    u16*   qkvb   = (u16*)  (w8 + 48840704);
    u16*   ffb    = (u16*)  (w8 + 74006528);     // CH*2048*2 ; attnob aliased at base
    u16*   attnob = ffb;

    // FF chunk rows: biggest that fits scratch (lin2 grid = CH/128 blocks)
    int CH = 4096;
    if      (ws_size >= 74006528ull + 134217728ull) CH = 32768;
    else if (ws_size >= 74006528ull +  33554432ull) CH = 8192;
    int nc = 32768 / CH;

    // weight conversions (per-launch, deterministic)
    cvt_f2b_kernel<<<4,   256, 0, stream>>>(dm_w,       wb_dm, 8192);
    cvt_f2b_kernel<<<48,  256, 0, stream>>>(in_proj_w,  wb_ip, 98304);
    cvt_f2b_kernel<<<16,  256, 0, stream>>>(out_proj_w, wb_op, 32768);
    cvt_f2b_kernel<<<256, 256, 0, stream>>>(lin1_w,     wb_l1, 524288);
    cvt_f2b_kernel<<<256, 256, 0, stream>>>(lin2_w,     wb_l2, 524288);

    tm_kernel<<<(BB * SS + 255) / 256, 256, 0, stream>>>(mask, tm);
    xw_kernel<<<BB * SS / XW_RPB, 192, 0, stream>>>(x, mask, delta, gru_w_ih, gru_b_ih, xw);
    gru_scan_kernel<<<BB, 64, 0, stream>>>(gru_w_hh, gru_b_hh, xw, hsb);

    // z = hs @ dm_w^T + dm_b  -> fp32 z + bf16 zb
    mfma_gemm<3, false><<<dim3(256, 1), 256, 0, stream>>>(hsb, wb_dm, dm_b, z, zb, 32768, 128, 64);

    for (int l = 0; l < LL; ++l) {
        mfma_gemm<2, false><<<dim3(256, 3), 256, 0, stream>>>(
            zb, wb_ip + (size_t)l * 49152, in_proj_b + l * 384, nullptr, qkvb, 32768, 384, 128);
        attn_kernel<<<BB * NHH, 256, 0, stream>>>(qkvb, tm, attnob);
        mfma_gemm<1, false><<<dim3(256, 1), 256, 0, stream>>>(
            attnob, wb_op + (size_t)l * 16384, out_proj_b + l * 128, proj, nullptr, 32768, 128, 128);
        resln_kernel<<<BB * SS / 4, 256, 0, stream>>>(z, proj, ln1_s + l * 128, ln1_bb + l * 128, zb);
        for (int c = 0; c < nc; ++c) {
            mfma_gemm<2, true><<<dim3(CH / 128, 16), 256, 0, stream>>>(
                zb + (size_t)c * CH * 128, wb_l1 + (size_t)l * 262144, lin1_b + l * 2048,
                nullptr, ffb, CH, 2048, 128);
            mfma_gemm<1, false><<<dim3(CH / 128, 1), 256, 0, stream>>>(
                ffb, wb_l2 + (size_t)l * 262144, lin2_b + l * 128,
                proj + (size_t)c * CH * 128, nullptr, CH, 128, 2048);
        }
        resln_kernel<<<BB * SS / 4, 256, 0, stream>>>(z, proj, ln2_s + l * 128, ln2_bb + l * 128, zb);
    }

    score_kernel<<<BB * SS / 64, 256, 0, stream>>>(z, score_w, score_b, tm, scores);
    pool_kernel<<<BB, 256, 0, stream>>>(z, scores, pooled);
    head_kernel<<<BB, 128, 0, stream>>>(pooled, reg_w, reg_b, bin_w, bin_b, window_id, out);
}

// Round 3
// 739.023 us; speedup vs baseline: 2.6383x; 1.0851x over previous
//
#include <hip/hip_runtime.h>

typedef __attribute__((ext_vector_type(8))) short short8;
typedef __attribute__((ext_vector_type(4))) float f32x4;
typedef unsigned short u16;

#define BB   128
#define SS   256
#define FIN  40
#define HH   64
#define DD   128
#define NHH  4
#define LL   2
#define NEGV (-1e9f)

__device__ __forceinline__ u16 f2b(float f) {
    unsigned u = __float_as_uint(f);
    return (u16)((u + 0x7FFFu + ((u >> 16) & 1u)) >> 16);
}
__device__ __forceinline__ float b2f(u16 u) {
    return __uint_as_float(((unsigned)u) << 16);
}

// ---------------------------------------------------------------- merged fp32 -> bf16 weight convert
// block ranges: dm 4 [0,4) | ip 48 [4,52) | op 16 [52,68) | l1 256 [68,324) | l2 256 [324,580)
__global__ __launch_bounds__(256) void cvt_all_kernel(const float* __restrict__ dm_w,
                                                      const float* __restrict__ ip_w,
                                                      const float* __restrict__ op_w,
                                                      const float* __restrict__ l1_w,
                                                      const float* __restrict__ l2_w,
                                                      u16* __restrict__ o_dm, u16* __restrict__ o_ip,
                                                      u16* __restrict__ o_op, u16* __restrict__ o_l1,
                                                      u16* __restrict__ o_l2) {
    int blk = blockIdx.x;
    const float* s; u16* d; int off;
    if      (blk < 4)   { s = dm_w; d = o_dm; off = blk; }
    else if (blk < 52)  { s = ip_w; d = o_ip; off = blk - 4; }
    else if (blk < 68)  { s = op_w; d = o_op; off = blk - 52; }
    else if (blk < 324) { s = l1_w; d = o_l1; off = blk - 68; }
    else                { s = l2_w; d = o_l2; off = blk - 324; }
    int i = (off * 256 + threadIdx.x) * 8;
    float4 a = *(const float4*)&s[i];
    float4 b = *(const float4*)&s[i + 4];
    short8 o;
    o[0] = (short)f2b(a.x); o[1] = (short)f2b(a.y); o[2] = (short)f2b(a.z); o[3] = (short)f2b(a.w);
    o[4] = (short)f2b(b.x); o[5] = (short)f2b(b.y); o[6] = (short)f2b(b.z); o[7] = (short)f2b(b.w);
    *(short8*)&d[i] = o;
}

// ---------------------------------------------------------------- time mask
__global__ __launch_bounds__(256) void tm_kernel(const float* __restrict__ mask,
                                                 float* __restrict__ tm) {
    int i = blockIdx.x * blockDim.x + threadIdx.x;
    if (i >= BB * SS) return;
    const float* m = mask + (size_t)i * FIN;
    float s = 0.f;
    for (int f = 0; f < FIN; ++f) s += m[f];
    tm[i] = (s > 0.f) ? 1.f : 0.f;
}

// ------------------------------------------------- xw = concat(x,mask,delta) @ W_ih^T + b_ih
#define XW_RPB 16
__global__ __launch_bounds__(192) void xw_kernel(const float* __restrict__ x,
                                                 const float* __restrict__ mask,
                                                 const float* __restrict__ delta,
                                                 const float* __restrict__ w_ih,
                                                 const float* __restrict__ b_ih,
                                                 float* __restrict__ xw) {
    __shared__ float inp[XW_RPB][120];
    __shared__ float wl[192][21];
    int row0 = blockIdx.x * XW_RPB;
    int tid  = threadIdx.x;

    for (int idx = tid; idx < XW_RPB * 120; idx += 192) {
        int r = idx / 120, k = idx % 120;
        int g = row0 + r;
        float v;
        if (k < 40)      v = x[(size_t)g * FIN + k];
        else if (k < 80) v = mask[(size_t)g * FIN + (k - 40)];
        else             v = delta[(size_t)g * FIN + (k - 80)];
        inp[r][k] = v;
    }

    float acc[XW_RPB];
#pragma unroll
    for (int r = 0; r < XW_RPB; ++r) acc[r] = 0.f;

    for (int kt = 0; kt < 6; ++kt) {
        __syncthreads();
        for (int idx = tid; idx < 192 * 20; idx += 192) {
            int r = idx / 20, k = idx % 20;
            wl[r][k] = w_ih[(size_t)r * 120 + kt * 20 + k];
        }
        __syncthreads();
#pragma unroll
        for (int kk = 0; kk < 20; ++kk) {
            float w = wl[tid][kk];
            int kg = kt * 20 + kk;
#pragma unroll
            for (int r = 0; r < XW_RPB; ++r) acc[r] += w * inp[r][kg];
        }
    }
    float bias = b_ih[tid];
    for (int r = 0; r < XW_RPB; ++r)
        xw[(size_t)(row0 + r) * 192 + tid] = acc[r] + bias;
}

// ---------------------------------------------------------------- GRU scan: 1 wave/batch-row
// weights in native float4 arrays, fully-unrolled constant indices -> VGPR-resident.
// single wave => lockstep => NO barriers needed (ds ordering via lgkmcnt).
__global__ __launch_bounds__(64, 1) void gru_scan_kernel(const float* __restrict__ w_hh,
                                                         const float* __restrict__ b_hh,
                                                         const float* __restrict__ xw,
                                                         u16* __restrict__ hsb) {
    __shared__ float h[HH];
    int b = blockIdx.x, j = threadIdx.x;

    float4 wr4[16], wz4[16], wn4[16];
    const float4* pr = (const float4*)(w_hh + (size_t)j * HH);
    const float4* pz = (const float4*)(w_hh + (size_t)(64 + j) * HH);
    const float4* pn = (const float4*)(w_hh + (size_t)(128 + j) * HH);
#pragma unroll
    for (int k = 0; k < 16; ++k) { wr4[k] = pr[k]; wz4[k] = pz[k]; wn4[k] = pn[k]; }

    float br = b_hh[j], bz = b_hh[64 + j], bn = b_hh[128 + j];
    h[j] = 0.f;
    float hj = 0.f;
    const float* xwb = xw + (size_t)b * SS * 192;
    float xr = xwb[j], xz = xwb[64 + j], xn = xwb[128 + j];
    __builtin_amdgcn_s_waitcnt(0);   // h[] init visible (same wave anyway)

    for (int t = 0; t < SS; ++t) {
        int tn = (t + 1 < SS) ? t + 1 : t;       // prefetch next xw (hides HBM latency)
        float pxr = xwb[(size_t)tn * 192 + j];
        float pxz = xwb[(size_t)tn * 192 + 64 + j];
        float pxn = xwb[(size_t)tn * 192 + 128 + j];

        // 6 independent accumulator chains (2 per gate)
        float ar0 = br, az0 = bz, an0 = bn, ar1 = 0.f, az1 = 0.f, an1 = 0.f;
#pragma unroll
        for (int k = 0; k < 8; ++k) {
            float4 h0 = *(const float4*)&h[k * 8];       // LDS broadcast
            float4 h1 = *(const float4*)&h[k * 8 + 4];
            float4 a = wr4[2 * k], bq = wr4[2 * k + 1];
            ar0 += a.x*h0.x + a.y*h0.y + a.z*h0.z + a.w*h0.w;
            ar1 += bq.x*h1.x + bq.y*h1.y + bq.z*h1.z + bq.w*h1.w;
            a = wz4[2 * k]; bq = wz4[2 * k + 1];
            az0 += a.x*h0.x + a.y*h0.y + a.z*h0.z + a.w*h0.w;
            az1 += bq.x*h1.x + bq.y*h1.y + bq.z*h1.z + bq.w*h1.w;
            a = wn4[2 * k]; bq = wn4[2 * k + 1];
            an0 += a.x*h0.x + a.y*h0.y + a.z*h0.z + a.w*h0.w;
            an1 += bq.x*h1.x + bq.y*h1.y + bq.z*h1.z + bq.w*h1.w;
        }
        float ar = ar0 + ar1, az = az0 + az1, an = an0 + an1;
        float r  = 1.f / (1.f + __expf(-(xr + ar)));
        float zg = 1.f / (1.f + __expf(-(xz + az)));
        float nx = xn + r * an;
        float n  = 2.f / (1.f + __expf(-2.f * nx)) - 1.f;   // tanh
        hj = (1.f - zg) * n + zg * hj;
        h[j] = hj;                                    // in-wave lockstep: no barrier
        hsb[((size_t)b * SS + t) * HH + j] = f2b(hj);
        xr = pxr; xz = pxz; xn = pxn;
    }
}

// ---------------------------------------------------------------- bf16 MFMA GEMM (m97 structure)
__device__ __forceinline__ void gl_lds16(const void* g, void* s) {
    __builtin_amdgcn_global_load_lds(
        (const __attribute__((address_space(1))) void*)g,
        (__attribute__((address_space(3))) void*)s, 16, 0, 0);
}

template <int OUTMODE, bool RELU>   // OUTMODE bit0: fp32 C, bit1: bf16 Cb
__global__ __launch_bounds__(256) void mfma_gemm(const u16* __restrict__ A,
                                                 const u16* __restrict__ W,
                                                 const float* __restrict__ bias,
                                                 float* __restrict__ C,
                                                 u16* __restrict__ Cb,
                                                 int M, int N, int K) {
    __shared__ __align__(16) u16 Al[128 * 32];
    __shared__ __align__(16) u16 Bl[128 * 32];
    int bm = blockIdx.x, bn = blockIdx.y;
    int tid = threadIdx.x;
    int w = tid >> 6, lane = tid & 63;
    int wrow = (w >> 1) * 64, wcol = (w & 1) * 64;
    int fr = lane & 15, fk = (lane >> 4) * 8;
    int srow = lane >> 2;
    int scol = (lane & 3) * 8;

    const u16* Ag = A + ((size_t)bm * 128) * K + scol;
    const u16* Wg = W + ((size_t)bn * 128) * K + scol;

    f32x4 acc[4][4];
#pragma unroll
    for (int i = 0; i < 4; ++i)
#pragma unroll
        for (int jj = 0; jj < 4; ++jj) acc[i][jj] = (f32x4){0.f, 0.f, 0.f, 0.f};

    for (int kt = 0; kt < K; kt += 32) {
        __syncthreads();
#pragma unroll
        for (int i = 0; i < 2; ++i) {
            int c = w + i * 4;
            int row = c * 16 + srow;
            gl_lds16(Ag + (size_t)row * K + kt, &Al[c * 512]);
            gl_lds16(Wg + (size_t)row * K + kt, &Bl[c * 512]);
        }
        __syncthreads();
        short8 a[4], bq[4];
#pragma unroll
        for (int m = 0; m < 4; ++m)
            a[m] = *(const short8*)&Al[(wrow + m * 16 + fr) * 32 + fk];
#pragma unroll
        for (int n = 0; n < 4; ++n)
            bq[n] = *(const short8*)&Bl[(wcol + n * 16 + fr) * 32 + fk];
#pragma unroll
        for (int m = 0; m < 4; ++m)
#pragma unroll
            for (int n = 0; n < 4; ++n)
                acc[m][n] = __builtin_amdgcn_mfma_f32_16x16x32_bf16(a[m], bq[n], acc[m][n], 0, 0, 0);
    }

    float bv[4];
#pragma unroll
    for (int n = 0; n < 4; ++n) bv[n] = bias[bn * 128 + wcol + n * 16 + (lane & 15)];
#pragma unroll
    for (int m = 0; m < 4; ++m) {
#pragma unroll
        for (int j = 0; j < 4; ++j) {
            int row = bm * 128 + wrow + m * 16 + (lane >> 4) * 4 + j;
#pragma unroll
            for (int n = 0; n < 4; ++n) {
                int col = bn * 128 + wcol + n * 16 + (lane & 15);
                float v = acc[m][n][j] + bv[n];
                if (RELU) v = fmaxf(v, 0.f);
                if (OUTMODE & 1) C[(size_t)row * N + col] = v;
                if (OUTMODE & 2) Cb[(size_t)row * N + col] = f2b(v);
            }
        }
    }
}

// ---------------------------------------------------------------- attention (bf16 qkv in, bf16 out)
__global__ __launch_bounds__(256) void attn_kernel(const u16* __restrict__ qkv,
                                                   const float* __restrict__ tm,
                                                   u16* __restrict__ attno) {
    int bh = blockIdx.x;
    int b = bh / NHH, hd = bh % NHH;
    int s = threadIdx.x;

    __shared__ float Kt[64][32];
    __shared__ float Vt[64][32];
    __shared__ float tms[64];

    float q[32];
    const u16* qrow = qkv + ((size_t)b * SS + s) * 384 + hd * 32;
#pragma unroll
    for (int j = 0; j < 32; j += 8) {
        short8 v = *(const short8*)&qrow[j];
#pragma unroll
        for (int jj = 0; jj < 8; ++jj) q[j + jj] = b2f((u16)v[jj]);
    }
    const float scale = 0.17677669529663687f;
    float denom = 0.f;
    float o[32];
#pragma unroll
    for (int j = 0; j < 32; ++j) o[j] = 0.f;

    for (int kt = 0; kt < SS; kt += 64) {
        __syncthreads();
        {
            int r = s >> 2, c = (s & 3) * 8;
            const u16* kb = qkv + ((size_t)b * SS + kt + r) * 384 + 128 + hd * 32 + c;
            const u16* vb = qkv + ((size_t)b * SS + kt + r) * 384 + 256 + hd * 32 + c;
            short8 kv = *(const short8*)kb;
            short8 vv = *(const short8*)vb;
#pragma unroll
            for (int jj = 0; jj < 8; ++jj) {
                Kt[r][c + jj] = b2f((u16)kv[jj]);
                Vt[r][c + jj] = b2f((u16)vv[jj]);
            }
        }
        if (s < 64) tms[s] = tm[b * SS + kt + s];
        __syncthreads();
        for (int k = 0; k < 64; ++k) {
            float acc = 0.f;
#pragma unroll
            for (int j = 0; j < 32; ++j) acc += q[j] * Kt[k][j];
            float sc = acc * scale + (tms[k] > 0.f ? 0.f : NEGV);
            float e = __expf(sc);
            denom += e;
#pragma unroll
            for (int j = 0; j < 32; ++j) o[j] += e * Vt[k][j];
        }
    }
    float inv = 1.f / denom;
    u16* orow = attno + ((size_t)b * SS + s) * DD + hd * 32;
#pragma unroll
    for (int j = 0; j < 32; j += 8) {
        short8 ov;
#pragma unroll
        for (int jj = 0; jj < 8; ++jj) ov[jj] = (short)f2b(o[j + jj] * inv);
        *(short8*)&orow[j] = ov;
    }
}

// ---------------------------------------------------------------- residual + LN (+ bf16 copy)
__global__ __launch_bounds__(256) void resln_kernel(float* __restrict__ z,
                                                    const float* __restrict__ addv,
                                                    const float* __restrict__ sg,
                                                    const float* __restrict__ bg,
                                                    u16* __restrict__ zb) {
    int row  = blockIdx.x * 4 + (threadIdx.x >> 6);
    int lane = threadIdx.x & 63;
    float2 zv = *(const float2*)&z[(size_t)row * DD + lane * 2];
    float2 av = *(const float2*)&addv[(size_t)row * DD + lane * 2];
    float x0 = zv.x + av.x, x1 = zv.y + av.y;
    float sum = x0 + x1;
#pragma unroll
    for (int off = 32; off; off >>= 1) sum += __shfl_xor(sum, off);
    float mean = sum * (1.f / 128.f);
    float d0 = x0 - mean, d1 = x1 - mean;
    float vs = d0 * d0 + d1 * d1;
#pragma unroll
    for (int off = 32; off; off >>= 1) vs += __shfl_xor(vs, off);
    float rstd = rsqrtf(vs * (1.f / 128.f) + 1e-5f);
    float2 sv = *(const float2*)&sg[lane * 2];
    float2 bv = *(const float2*)&bg[lane * 2];
    float o0 = d0 * rstd * sv.x + bv.x;
    float o1 = d1 * rstd * sv.y + bv.y;
    *(float2*)&z[(size_t)row * DD + lane * 2] = (float2){o0, o1};
    u16 b0 = f2b(o0), b1 = f2b(o1);
    unsigned packed = (unsigned)b0 | ((unsigned)b1 << 16);
    *(unsigned*)&zb[(size_t)row * DD + lane * 2] = packed;
}

// ---------------------------------------------------------------- score = z @ score_w^T + b (masked)
__global__ __launch_bounds__(256) void score_kernel(const float* __restrict__ z,
                                                    const float* __restrict__ score_w,
                                                    const float* __restrict__ score_b,
                                                    const float* __restrict__ tm,
                                                    float* __restrict__ scores) {
    int row = blockIdx.x * 64 + (threadIdx.x >> 2);
    int c = threadIdx.x & 3;
    const float* zr = z + (size_t)row * DD + c * 32;
    const float* wr = score_w + c * 32;
    float acc = 0.f;
#pragma unroll
    for (int j = 0; j < 32; j += 4) {
        float4 a = *(const float4*)(zr + j), w = *(const float4*)(wr + j);
        acc += a.x * w.x + a.y * w.y + a.z * w.z + a.w * w.w;
    }
    acc += __shfl_xor(acc, 1);
    acc += __shfl_xor(acc, 2);
    if (c == 0) {
        float sc = acc + score_b[0];
        scores[row] = (tm[row] > 0.f) ? sc : NEGV;
    }
}

// ---------------------------------------------------------------- softmax over S + weighted pool
__global__ __launch_bounds__(256) void pool_kernel(const float* __restrict__ z,
                                                   const float* __restrict__ scores,
                                                   float* __restrict__ pooled) {
    int b = blockIdx.x;
    int tid = threadIdx.x;
    __shared__ float al[SS];
    __shared__ float red[8];
    __shared__ float pp[2][128];

    float sc = scores[b * SS + tid];
    float m = sc;
#pragma unroll
    for (int off = 32; off; off >>= 1) m = fmaxf(m, __shfl_xor(m, off));
    if ((tid & 63) == 0) red[tid >> 6] = m;
    __syncthreads();
    m = fmaxf(fmaxf(red[0], red[1]), fmaxf(red[2], red[3]));
    float e = __expf(sc - m);
    float ssum = e;
#pragma unroll
    for (int off = 32; off; off >>= 1) ssum += __shfl_xor(ssum, off);
    if ((tid & 63) == 0) red[4 + (tid >> 6)] = ssum;
    __syncthreads();
    ssum = red[4] + red[5] + red[6] + red[7];
    al[tid] = e / ssum;
    __syncthreads();

    int d = tid & 127, half = tid >> 7;
    float acc = 0.f;
    for (int t = half; t < SS; t += 2) acc += al[t] * z[((size_t)b * SS + t) * DD + d];
    pp[half][d] = acc;
    __syncthreads();
    if (tid < 128) pooled[b * 128 + tid] = pp[0][tid] + pp[1][tid];
}

// ---------------------------------------------------------------- routed heads
__global__ __launch_bounds__(128) void head_kernel(const float* __restrict__ pooled,
                                                   const float* __restrict__ reg_w,
                                                   const float* __restrict__ reg_b,
                                                   const float* __restrict__ bin_w,
                                                   const float* __restrict__ bin_b,
                                                   const int* __restrict__ wid,
                                                   float* __restrict__ out) {
    int b = blockIdx.x, tid = threadIdx.x;
    __shared__ float p[128];
    p[tid] = pooled[b * 128 + tid];
    __syncthreads();
    if (tid < 9) {
        int w = wid[b];
        const float* wrow;
        float bias;
        if (tid < 8) { wrow = reg_w + ((size_t)w * 8 + tid) * 128; bias = reg_b[w * 8 + tid]; }
        else         { wrow = bin_w + (size_t)w * 128;             bias = bin_b[w]; }
        float acc = bias;
        for (int k = 0; k < 128; ++k) acc += wrow[k] * p[k];
        if (tid < 8) out[b * 8 + tid] = acc;
        else         out[1024 + b] = acc;
    }
}

// ================================================================ host
extern "C" void kernel_launch(void* const* d_in, const int* in_sizes, int n_in,
                              void* d_out, int out_size, void* d_ws, size_t ws_size,
                              hipStream_t stream) {
    const float* x         = (const float*)d_in[0];
    const float* mask      = (const float*)d_in[1];
    const float* delta     = (const float*)d_in[2];
    const float* gru_w_ih  = (const float*)d_in[3];
    const float* gru_w_hh  = (const float*)d_in[4];
    const float* gru_b_ih  = (const float*)d_in[5];
    const float* gru_b_hh  = (const float*)d_in[6];
    const float* dm_w      = (const float*)d_in[7];
    const float* dm_b      = (const float*)d_in[8];
    const float* in_proj_w = (const float*)d_in[9];
    const float* in_proj_b = (const float*)d_in[10];
    const float* out_proj_w= (const float*)d_in[11];
    const float* out_proj_b= (const float*)d_in[12];
    const float* lin1_w    = (const float*)d_in[13];
    const float* lin1_b    = (const float*)d_in[14];
    const float* lin2_w    = (const float*)d_in[15];
    const float* lin2_b    = (const float*)d_in[16];
    const float* ln1_s     = (const float*)d_in[17];
    const float* ln1_bb    = (const float*)d_in[18];
    const float* ln2_s     = (const float*)d_in[19];
    const float* ln2_bb    = (const float*)d_in[20];
    const float* score_w   = (const float*)d_in[21];
    const float* score_b   = (const float*)d_in[22];
    const float* reg_w     = (const float*)d_in[23];
    const float* reg_b     = (const float*)d_in[24];
    const float* bin_w     = (const float*)d_in[25];
    const float* bin_b     = (const float*)d_in[26];
    const int*   window_id = (const int*)d_in[27];
    float* out = (float*)d_out;

    char* w8 = (char*)d_ws;
    float* z      = (float*)(w8 + 0);            // 16,777,216
    u16*   zb     = (u16*)  (w8 + 16777216);     //  8,388,608
    float* proj   = (float*)(w8 + 25165824);     // 16,777,216
    u16*   hsb    = (u16*)  (w8 + 41943040);     //  4,194,304
    u16*   wb_dm  = (u16*)  (w8 + 46137344);     //     16,384
    u16*   wb_ip  = (u16*)  (w8 + 46153728);     //    196,608
    u16*   wb_op  = (u16*)  (w8 + 46350336);     //     65,536
    u16*   wb_l1  = (u16*)  (w8 + 46415872);     //  1,048,576
    u16*   wb_l2  = (u16*)  (w8 + 47464448);     //  1,048,576
    float* tm     = (float*)(w8 + 48513024);     //    131,072
    float* scores = (float*)(w8 + 48644096);     //    131,072
    float* pooled = (float*)(w8 + 48775168);     //     65,536
    float* xw     = (float*)(w8 + 48840704);     // 25,165,824 (GRU: xw fp32 | later: qkvb bf16)
    u16*   qkvb   = (u16*)  (w8 + 48840704);
    u16*   ffb    = (u16*)  (w8 + 74006528);     // CH*2048*2 ; attnob aliased at base
    u16*   attnob = ffb;

    int CH = 4096;
    if      (ws_size >= 74006528ull + 134217728ull) CH = 32768;
    else if (ws_size >= 74006528ull +  33554432ull) CH = 8192;
    int nc = 32768 / CH;

    cvt_all_kernel<<<580, 256, 0, stream>>>(dm_w, in_proj_w, out_proj_w, lin1_w, lin2_w,
                                            wb_dm, wb_ip, wb_op, wb_l1, wb_l2);

    tm_kernel<<<(BB * SS + 255) / 256, 256, 0, stream>>>(mask, tm);
    xw_kernel<<<BB * SS / XW_RPB, 192, 0, stream>>>(x, mask, delta, gru_w_ih, gru_b_ih, xw);
    gru_scan_kernel<<<BB, 64, 0, stream>>>(gru_w_hh, gru_b_hh, xw, hsb);

    mfma_gemm<3, false><<<dim3(256, 1), 256, 0, stream>>>(hsb, wb_dm, dm_b, z, zb, 32768, 128, 64);

    for (int l = 0; l < LL; ++l) {
        mfma_gemm<2, false><<<dim3(256, 3), 256, 0, stream>>>(
            zb, wb_ip + (size_t)l * 49152, in_proj_b + l * 384, nullptr, qkvb, 32768, 384, 128);
        attn_kernel<<<BB * NHH, 256, 0, stream>>>(qkvb, tm, attnob);
        mfma_gemm<1, false><<<dim3(256, 1), 256, 0, stream>>>(
            attnob, wb_op + (size_t)l * 16384, out_proj_b + l * 128, proj, nullptr, 32768, 128, 128);
        resln_kernel<<<BB * SS / 4, 256, 0, stream>>>(z, proj, ln1_s + l * 128, ln1_bb + l * 128, zb);
        for (int c = 0; c < nc; ++c) {
            mfma_gemm<2, true><<<dim3(CH / 128, 16), 256, 0, stream>>>(
                zb + (size_t)c * CH * 128, wb_l1 + (size_t)l * 262144, lin1_b + l * 2048,
                nullptr, ffb, CH, 2048, 128);
            mfma_gemm<1, false><<<dim3(CH / 128, 1), 256, 0, stream>>>(
                ffb, wb_l2 + (size_t)l * 262144, lin2_b + l * 128,
                proj + (size_t)c * CH * 128, nullptr, CH, 128, 2048);
        }
        resln_kernel<<<BB * SS / 4, 256, 0, stream>>>(z, proj, ln2_s + l * 128, ln2_bb + l * 128, zb);
    }

    score_kernel<<<BB * SS / 64, 256, 0, stream>>>(z, score_w, score_b, tm, scores);
    pool_kernel<<<BB, 256, 0, stream>>>(z, scores, pooled);
    head_kernel<<<BB, 128, 0, stream>>>(pooled, reg_w, reg_b, bin_w, bin_b, window_id, out);
}

// Round 4
// 687.970 us; speedup vs baseline: 2.8340x; 1.0742x over previous
//
#include <hip/hip_runtime.h>

typedef __attribute__((ext_vector_type(8))) short short8;
typedef __attribute__((ext_vector_type(4))) float f32x4;
typedef unsigned short u16;

#define BB   128
#define SS   256
#define FIN  40
#define HH   64
#define DD   128
#define NHH  4
#define LL   2
#define NEGV (-1e9f)

__device__ __forceinline__ u16 f2b(float f) {
    unsigned u = __float_as_uint(f);
    return (u16)((u + 0x7FFFu + ((u >> 16) & 1u)) >> 16);
}
__device__ __forceinline__ float b2f(u16 u) {
    return __uint_as_float(((unsigned)u) << 16);
}

// ---------------------------------------------------------------- merged fp32 -> bf16 weight convert
__global__ __launch_bounds__(256) void cvt_all_kernel(const float* __restrict__ dm_w,
                                                      const float* __restrict__ ip_w,
                                                      const float* __restrict__ op_w,
                                                      const float* __restrict__ l1_w,
                                                      const float* __restrict__ l2_w,
                                                      u16* __restrict__ o_dm, u16* __restrict__ o_ip,
                                                      u16* __restrict__ o_op, u16* __restrict__ o_l1,
                                                      u16* __restrict__ o_l2) {
    int blk = blockIdx.x;
    const float* s; u16* d; int off;
    if      (blk < 4)   { s = dm_w; d = o_dm; off = blk; }
    else if (blk < 52)  { s = ip_w; d = o_ip; off = blk - 4; }
    else if (blk < 68)  { s = op_w; d = o_op; off = blk - 52; }
    else if (blk < 324) { s = l1_w; d = o_l1; off = blk - 68; }
    else                { s = l2_w; d = o_l2; off = blk - 324; }
    int i = (off * 256 + threadIdx.x) * 8;
    float4 a = *(const float4*)&s[i];
    float4 b = *(const float4*)&s[i + 4];
    short8 o;
    o[0] = (short)f2b(a.x); o[1] = (short)f2b(a.y); o[2] = (short)f2b(a.z); o[3] = (short)f2b(a.w);
    o[4] = (short)f2b(b.x); o[5] = (short)f2b(b.y); o[6] = (short)f2b(b.z); o[7] = (short)f2b(b.w);
    *(short8*)&d[i] = o;
}

// ---------------------------------------------------------------- time mask
__global__ __launch_bounds__(256) void tm_kernel(const float* __restrict__ mask,
                                                 float* __restrict__ tm) {
    int i = blockIdx.x * blockDim.x + threadIdx.x;
    if (i >= BB * SS) return;
    const float* m = mask + (size_t)i * FIN;
    float s = 0.f;
    for (int f = 0; f < FIN; ++f) s += m[f];
    tm[i] = (s > 0.f) ? 1.f : 0.f;
}

// ------------------------------------------------- xw = concat(x,mask,delta) @ W_ih^T + b_ih
#define XW_RPB 16
__global__ __launch_bounds__(192) void xw_kernel(const float* __restrict__ x,
                                                 const float* __restrict__ mask,
                                                 const float* __restrict__ delta,
                                                 const float* __restrict__ w_ih,
                                                 const float* __restrict__ b_ih,
                                                 float* __restrict__ xw) {
    __shared__ float inp[XW_RPB][120];
    __shared__ float wl[192][21];
    int row0 = blockIdx.x * XW_RPB;
    int tid  = threadIdx.x;

    for (int idx = tid; idx < XW_RPB * 120; idx += 192) {
        int r = idx / 120, k = idx % 120;
        int g = row0 + r;
        float v;
        if (k < 40)      v = x[(size_t)g * FIN + k];
        else if (k < 80) v = mask[(size_t)g * FIN + (k - 40)];
        else             v = delta[(size_t)g * FIN + (k - 80)];
        inp[r][k] = v;
    }

    float acc[XW_RPB];
#pragma unroll
    for (int r = 0; r < XW_RPB; ++r) acc[r] = 0.f;

    for (int kt = 0; kt < 6; ++kt) {
        __syncthreads();
        for (int idx = tid; idx < 192 * 20; idx += 192) {
            int r = idx / 20, k = idx % 20;
            wl[r][k] = w_ih[(size_t)r * 120 + kt * 20 + k];
        }
        __syncthreads();
#pragma unroll
        for (int kk = 0; kk < 20; ++kk) {
            float w = wl[tid][kk];
            int kg = kt * 20 + kk;
#pragma unroll
            for (int r = 0; r < XW_RPB; ++r) acc[r] += w * inp[r][kg];
        }
    }
    float bias = b_ih[tid];
    for (int r = 0; r < XW_RPB; ++r)
        xw[(size_t)(row0 + r) * 192 + tid] = acc[r] + bias;
}

// ---------------------------------------------------------------- GRU scan: 3 waves/batch-row
// thread j owns gate-row j (64 weights = 16 float4, asm-pinned); h broadcast via LDS.
__global__ __launch_bounds__(192, 1) void gru_scan_kernel(const float* __restrict__ w_hh,
                                                          const float* __restrict__ b_hh,
                                                          const float* __restrict__ xw,
                                                          u16* __restrict__ hsb) {
    __shared__ float h[HH];
    __shared__ float gh[3 * HH];
    __shared__ float xs[3 * HH];
    int b = blockIdx.x, j = threadIdx.x;

    float4 w4[16];
    const float4* pw = (const float4*)(w_hh + (size_t)j * HH);
#pragma unroll
    for (int k = 0; k < 16; ++k) w4[k] = pw[k];
#pragma unroll
    for (int k = 0; k < 16; ++k)
        asm volatile("" : "+v"(w4[k].x), "+v"(w4[k].y), "+v"(w4[k].z), "+v"(w4[k].w));

    float bh = b_hh[j];
    if (j < HH) h[j] = 0.f;
    const float* xwb = xw + (size_t)b * SS * 192;
    float xv = xwb[j];
    __syncthreads();

    for (int t = 0; t < SS; ++t) {
        float px = xwb[(size_t)(t + 1 < SS ? t + 1 : t) * 192 + j];   // prefetch next step
        // 4 independent 16-FMA chains
        float a0 = bh, a1 = 0.f, a2 = 0.f, a3 = 0.f;
#pragma unroll
        for (int k = 0; k < 4; ++k) {
            float4 h0 = *(const float4*)&h[k * 16];
            float4 h1 = *(const float4*)&h[k * 16 + 4];
            float4 h2 = *(const float4*)&h[k * 16 + 8];
            float4 h3 = *(const float4*)&h[k * 16 + 12];
            float4 wa = w4[k * 4], wb = w4[k * 4 + 1], wc = w4[k * 4 + 2], wd = w4[k * 4 + 3];
            a0 += wa.x*h0.x + wa.y*h0.y + wa.z*h0.z + wa.w*h0.w;
            a1 += wb.x*h1.x + wb.y*h1.y + wb.z*h1.z + wb.w*h1.w;
            a2 += wc.x*h2.x + wc.y*h2.y + wc.z*h2.z + wc.w*h2.w;
            a3 += wd.x*h3.x + wd.y*h3.y + wd.z*h3.z + wd.w*h3.w;
        }
        gh[j] = (a0 + a1) + (a2 + a3);
        xs[j] = xv;
        __syncthreads();
        if (j < HH) {
            float r  = 1.f / (1.f + __expf(-(xs[j] + gh[j])));
            float zg = 1.f / (1.f + __expf(-(xs[64 + j] + gh[64 + j])));
            float nx = xs[128 + j] + r * gh[128 + j];
            float n  = 2.f / (1.f + __expf(-2.f * nx)) - 1.f;   // tanh
            float hj = (1.f - zg) * n + zg * h[j];
            h[j] = hj;
            hsb[((size_t)b * SS + t) * HH + j] = f2b(hj);
        }
        __syncthreads();
        xv = px;
    }
}

// ---------------------------------------------------------------- bf16 MFMA GEMM (m97 structure)
// MODE: 1=f32 C, 2=bf16 Cb, 3=both, 4=fused residual+LayerNorm (N must be 128, bn==0):
//       z_row = LN(z_old + acc + bias) * ln_s + ln_b  -> C (fp32, in/out) and Cb (bf16)
__device__ __forceinline__ void gl_lds16(const void* g, void* s) {
    __builtin_amdgcn_global_load_lds(
        (const __attribute__((address_space(1))) void*)g,
        (__attribute__((address_space(3))) void*)s, 16, 0, 0);
}

template <int MODE, bool RELU>
__global__ __launch_bounds__(256, 2) void mfma_gemm(const u16* __restrict__ A,
                                                    const u16* __restrict__ W,
                                                    const float* __restrict__ bias,
                                                    float* __restrict__ C,
                                                    u16* __restrict__ Cb,
                                                    const float* __restrict__ lns,
                                                    const float* __restrict__ lnb,
                                                    int M, int N, int K) {
    __shared__ __align__(16) u16 Al[128 * 32];
    __shared__ __align__(16) u16 Bl[128 * 32];
    __shared__ float lred[2][2][128];
    int bm = blockIdx.x, bn = blockIdx.y;
    int tid = threadIdx.x;
    int w = tid >> 6, lane = tid & 63;
    int wrow = (w >> 1) * 64, wcol = (w & 1) * 64;
    int fr = lane & 15, fk = (lane >> 4) * 8;
    int hi = lane >> 4;
    int srow = lane >> 2;
    int scol = (lane & 3) * 8;

    const u16* Ag = A + ((size_t)bm * 128) * K + scol;
    const u16* Wg = W + ((size_t)bn * 128) * K + scol;

    f32x4 acc[4][4];
#pragma unroll
    for (int i = 0; i < 4; ++i)
#pragma unroll
        for (int jj = 0; jj < 4; ++jj) acc[i][jj] = (f32x4){0.f, 0.f, 0.f, 0.f};

    for (int kt = 0; kt < K; kt += 32) {
        __syncthreads();
#pragma unroll
        for (int i = 0; i < 2; ++i) {
            int c = w + i * 4;
            int row = c * 16 + srow;
            gl_lds16(Ag + (size_t)row * K + kt, &Al[c * 512]);
            gl_lds16(Wg + (size_t)row * K + kt, &Bl[c * 512]);
        }
        __syncthreads();
        short8 a[4], bq[4];
#pragma unroll
        for (int m = 0; m < 4; ++m)
            a[m] = *(const short8*)&Al[(wrow + m * 16 + fr) * 32 + fk];
#pragma unroll
        for (int n = 0; n < 4; ++n)
            bq[n] = *(const short8*)&Bl[(wcol + n * 16 + fr) * 32 + fk];
#pragma unroll
        for (int m = 0; m < 4; ++m)
#pragma unroll
            for (int n = 0; n < 4; ++n)
                acc[m][n] = __builtin_amdgcn_mfma_f32_16x16x32_bf16(a[m], bq[n], acc[m][n], 0, 0, 0);
    }

    float bv[4];
#pragma unroll
    for (int n = 0; n < 4; ++n) bv[n] = bias[bn * 128 + wcol + n * 16 + fr];

    if (MODE == 4) {
        // ---- fused residual + LayerNorm (N==128, bn==0) ----
        float v[4][4][4];
#pragma unroll
        for (int m = 0; m < 4; ++m)
#pragma unroll
            for (int j = 0; j < 4; ++j) {
                int row = bm * 128 + wrow + m * 16 + hi * 4 + j;
#pragma unroll
                for (int n = 0; n < 4; ++n)
                    v[m][n][j] = acc[m][n][j] + bv[n] + C[(size_t)row * 128 + wcol + n * 16 + fr];
            }
#pragma unroll
        for (int m = 0; m < 4; ++m)
#pragma unroll
            for (int j = 0; j < 4; ++j) {
                float s = v[m][0][j] + v[m][1][j] + v[m][2][j] + v[m][3][j];
                float q = v[m][0][j]*v[m][0][j] + v[m][1][j]*v[m][1][j]
                        + v[m][2][j]*v[m][2][j] + v[m][3][j]*v[m][3][j];
#pragma unroll
                for (int off = 1; off <= 8; off <<= 1) {
                    s += __shfl_xor(s, off);
                    q += __shfl_xor(q, off);
                }
                if (fr == 0) {
                    int lrow = wrow + m * 16 + hi * 4 + j;
                    lred[0][w & 1][lrow] = s;
                    lred[1][w & 1][lrow] = q;
                }
            }
        __syncthreads();
        float sv[4], bb[4];
#pragma unroll
        for (int n = 0; n < 4; ++n) {
            sv[n] = lns[wcol + n * 16 + fr];
            bb[n] = lnb[wcol + n * 16 + fr];
        }
#pragma unroll
        for (int m = 0; m < 4; ++m)
#pragma unroll
            for (int j = 0; j < 4; ++j) {
                int lrow = wrow + m * 16 + hi * 4 + j;
                float mean = (lred[0][0][lrow] + lred[0][1][lrow]) * (1.f / 128.f);
                float msq  = (lred[1][0][lrow] + lred[1][1][lrow]) * (1.f / 128.f);
                float rstd = rsqrtf(msq - mean * mean + 1e-5f);
                int row = bm * 128 + lrow;
#pragma unroll
                for (int n = 0; n < 4; ++n) {
                    int col = wcol + n * 16 + fr;
                    float o = (v[m][n][j] - mean) * rstd * sv[n] + bb[n];
                    C[(size_t)row * 128 + col] = o;
                    Cb[(size_t)row * 128 + col] = f2b(o);
                }
            }
    } else {
#pragma unroll
        for (int m = 0; m < 4; ++m) {
#pragma unroll
            for (int j = 0; j < 4; ++j) {
                int row = bm * 128 + wrow + m * 16 + hi * 4 + j;
#pragma unroll
                for (int n = 0; n < 4; ++n) {
                    int col = bn * 128 + wcol + n * 16 + fr;
                    float vv = acc[m][n][j] + bv[n];
                    if (RELU) vv = fmaxf(vv, 0.f);
                    if (MODE & 1) C[(size_t)row * N + col] = vv;
                    if (MODE & 2) Cb[(size_t)row * N + col] = f2b(vv);
                }
            }
        }
    }
}

// ---------------------------------------------------------------- attention (bf16 qkv in, bf16 out)
__global__ __launch_bounds__(256) void attn_kernel(const u16* __restrict__ qkv,
                                                   const float* __restrict__ tm,
                                                   u16* __restrict__ attno) {
    int bh = blockIdx.x;
    int b = bh / NHH, hd = bh % NHH;
    int s = threadIdx.x;

    __shared__ float Kt[64][32];
    __shared__ float Vt[64][32];
    __shared__ float tms[64];

    float q[32];
    const u16* qrow = qkv + ((size_t)b * SS + s) * 384 + hd * 32;
#pragma unroll
    for (int j = 0; j < 32; j += 8) {
        short8 v = *(const short8*)&qrow[j];
#pragma unroll
        for (int jj = 0; jj < 8; ++jj) q[j + jj] = b2f((u16)v[jj]);
    }
    const float scale = 0.17677669529663687f;
    float denom = 0.f;
    float o[32];
#pragma unroll
    for (int j = 0; j < 32; ++j) o[j] = 0.f;

    for (int kt = 0; kt < SS; kt += 64) {
        __syncthreads();
        {
            int r = s >> 2, c = (s & 3) * 8;
            const u16* kb = qkv + ((size_t)b * SS + kt + r) * 384 + 128 + hd * 32 + c;
            const u16* vb = qkv + ((size_t)b * SS + kt + r) * 384 + 256 + hd * 32 + c;
            short8 kv = *(const short8*)kb;
            short8 vv = *(const short8*)vb;
#pragma unroll
            for (int jj = 0; jj < 8; ++jj) {
                Kt[r][c + jj] = b2f((u16)kv[jj]);
                Vt[r][c + jj] = b2f((u16)vv[jj]);
            }
        }
        if (s < 64) tms[s] = tm[b * SS + kt + s];
        __syncthreads();
        for (int k = 0; k < 64; ++k) {
            float acc = 0.f;
#pragma unroll
            for (int j = 0; j < 32; ++j) acc += q[j] * Kt[k][j];
            float sc = acc * scale + (tms[k] > 0.f ? 0.f : NEGV);
            float e = __expf(sc);
            denom += e;
#pragma unroll
            for (int j = 0; j < 32; ++j) o[j] += e * Vt[k][j];
        }
    }
    float inv = 1.f / denom;
    u16* orow = attno + ((size_t)b * SS + s) * DD + hd * 32;
#pragma unroll
    for (int j = 0; j < 32; j += 8) {
        short8 ov;
#pragma unroll
        for (int jj = 0; jj < 8; ++jj) ov[jj] = (short)f2b(o[j + jj] * inv);
        *(short8*)&orow[j] = ov;
    }
}

// ---------------------------------------------------------------- score = z @ score_w^T + b (masked)
__global__ __launch_bounds__(256) void score_kernel(const float* __restrict__ z,
                                                    const float* __restrict__ score_w,
                                                    const float* __restrict__ score_b,
                                                    const float* __restrict__ tm,
                                                    float* __restrict__ scores) {
    int row = blockIdx.x * 64 + (threadIdx.x >> 2);
    int c = threadIdx.x & 3;
    const float* zr = z + (size_t)row * DD + c * 32;
    const float* wr = score_w + c * 32;
    float acc = 0.f;
#pragma unroll
    for (int j = 0; j < 32; j += 4) {
        float4 a = *(const float4*)(zr + j), w = *(const float4*)(wr + j);
        acc += a.x * w.x + a.y * w.y + a.z * w.z + a.w * w.w;
    }
    acc += __shfl_xor(acc, 1);
    acc += __shfl_xor(acc, 2);
    if (c == 0) {
        float sc = acc + score_b[0];
        scores[row] = (tm[row] > 0.f) ? sc : NEGV;
    }
}

// ---------------------------------------------------------------- softmax over S + weighted pool
__global__ __launch_bounds__(256) void pool_kernel(const float* __restrict__ z,
                                                   const float* __restrict__ scores,
                                                   float* __restrict__ pooled) {
    int b = blockIdx.x;
    int tid = threadIdx.x;
    __shared__ float al[SS];
    __shared__ float red[8];
    __shared__ float pp[2][128];

    float sc = scores[b * SS + tid];
    float m = sc;
#pragma unroll
    for (int off = 32; off; off >>= 1) m = fmaxf(m, __shfl_xor(m, off));
    if ((tid & 63) == 0) red[tid >> 6] = m;
    __syncthreads();
    m = fmaxf(fmaxf(red[0], red[1]), fmaxf(red[2], red[3]));
    float e = __expf(sc - m);
    float ssum = e;
#pragma unroll
    for (int off = 32; off; off >>= 1) ssum += __shfl_xor(ssum, off);
    if ((tid & 63) == 0) red[4 + (tid >> 6)] = ssum;
    __syncthreads();
    ssum = red[4] + red[5] + red[6] + red[7];
    al[tid] = e / ssum;
    __syncthreads();

    int d = tid & 127, half = tid >> 7;
    float acc = 0.f;
    for (int t = half; t < SS; t += 2) acc += al[t] * z[((size_t)b * SS + t) * DD + d];
    pp[half][d] = acc;
    __syncthreads();
    if (tid < 128) pooled[b * 128 + tid] = pp[0][tid] + pp[1][tid];
}

// ---------------------------------------------------------------- routed heads
__global__ __launch_bounds__(128) void head_kernel(const float* __restrict__ pooled,
                                                   const float* __restrict__ reg_w,
                                                   const float* __restrict__ reg_b,
                                                   const float* __restrict__ bin_w,
                                                   const float* __restrict__ bin_b,
                                                   const int* __restrict__ wid,
                                                   float* __restrict__ out) {
    int b = blockIdx.x, tid = threadIdx.x;
    __shared__ float p[128];
    p[tid] = pooled[b * 128 + tid];
    __syncthreads();
    if (tid < 9) {
        int w = wid[b];
        const float* wrow;
        float bias;
        if (tid < 8) { wrow = reg_w + ((size_t)w * 8 + tid) * 128; bias = reg_b[w * 8 + tid]; }
        else         { wrow = bin_w + (size_t)w * 128;             bias = bin_b[w]; }
        float acc = bias;
        for (int k = 0; k < 128; ++k) acc += wrow[k] * p[k];
        if (tid < 8) out[b * 8 + tid] = acc;
        else         out[1024 + b] = acc;
    }
}

// ================================================================ host
extern "C" void kernel_launch(void* const* d_in, const int* in_sizes, int n_in,
                              void* d_out, int out_size, void* d_ws, size_t ws_size,
                              hipStream_t stream) {
    const float* x         = (const float*)d_in[0];
    const float* mask      = (const float*)d_in[1];
    const float* delta     = (const float*)d_in[2];
    const float* gru_w_ih  = (const float*)d_in[3];
    const float* gru_w_hh  = (const float*)d_in[4];
    const float* gru_b_ih  = (const float*)d_in[5];
    const float* gru_b_hh  = (const float*)d_in[6];
    const float* dm_w      = (const float*)d_in[7];
    const float* dm_b      = (const float*)d_in[8];
    const float* in_proj_w = (const float*)d_in[9];
    const float* in_proj_b = (const float*)d_in[10];
    const float* out_proj_w= (const float*)d_in[11];
    const float* out_proj_b= (const float*)d_in[12];
    const float* lin1_w    = (const float*)d_in[13];
    const float* lin1_b    = (const float*)d_in[14];
    const float* lin2_w    = (const float*)d_in[15];
    const float* lin2_b    = (const float*)d_in[16];
    const float* ln1_s     = (const float*)d_in[17];
    const float* ln1_bb    = (const float*)d_in[18];
    const float* ln2_s     = (const float*)d_in[19];
    const float* ln2_bb    = (const float*)d_in[20];
    const float* score_w   = (const float*)d_in[21];
    const float* score_b   = (const float*)d_in[22];
    const float* reg_w     = (const float*)d_in[23];
    const float* reg_b     = (const float*)d_in[24];
    const float* bin_w     = (const float*)d_in[25];
    const float* bin_b     = (const float*)d_in[26];
    const int*   window_id = (const int*)d_in[27];
    float* out = (float*)d_out;

    char* w8 = (char*)d_ws;
    float* z      = (float*)(w8 + 0);            // 16,777,216
    u16*   zb     = (u16*)  (w8 + 16777216);     //  8,388,608
    u16*   hsb    = (u16*)  (w8 + 25165824);     //  4,194,304
    u16*   wb_dm  = (u16*)  (w8 + 29360128);     //     16,384
    u16*   wb_ip  = (u16*)  (w8 + 29376512);     //    196,608
    u16*   wb_op  = (u16*)  (w8 + 29573120);     //     65,536
    u16*   wb_l1  = (u16*)  (w8 + 29638656);     //  1,048,576
    u16*   wb_l2  = (u16*)  (w8 + 30687232);     //  1,048,576
    float* tm     = (float*)(w8 + 31735808);     //    131,072
    float* scores = (float*)(w8 + 31866880);     //    131,072
    float* pooled = (float*)(w8 + 31997952);     //     65,536
    float* xw     = (float*)(w8 + 32063488);     // 25,165,824 (GRU: xw fp32 | later: qkvb bf16)
    u16*   qkvb   = (u16*)  (w8 + 32063488);
    u16*   ffb    = (u16*)  (w8 + 57229312);     // CH*2048*2 ; attnob aliased at base
    u16*   attnob = ffb;

    int CH = 4096;
    if      (ws_size >= 57229312ull + 134217728ull) CH = 32768;
    else if (ws_size >= 57229312ull +  33554432ull) CH = 8192;
    int nc = 32768 / CH;

    cvt_all_kernel<<<580, 256, 0, stream>>>(dm_w, in_proj_w, out_proj_w, lin1_w, lin2_w,
                                            wb_dm, wb_ip, wb_op, wb_l1, wb_l2);

    tm_kernel<<<(BB * SS + 255) / 256, 256, 0, stream>>>(mask, tm);
    xw_kernel<<<BB * SS / XW_RPB, 192, 0, stream>>>(x, mask, delta, gru_w_ih, gru_b_ih, xw);
    gru_scan_kernel<<<BB, 192, 0, stream>>>(gru_w_hh, gru_b_hh, xw, hsb);

    mfma_gemm<3, false><<<dim3(256, 1), 256, 0, stream>>>(
        hsb, wb_dm, dm_b, z, zb, nullptr, nullptr, 32768, 128, 64);

    for (int l = 0; l < LL; ++l) {
        mfma_gemm<2, false><<<dim3(256, 3), 256, 0, stream>>>(
            zb, wb_ip + (size_t)l * 49152, in_proj_b + l * 384, nullptr, qkvb,
            nullptr, nullptr, 32768, 384, 128);
        attn_kernel<<<BB * NHH, 256, 0, stream>>>(qkvb, tm, attnob);
        // out_proj + residual + LN1 fused
        mfma_gemm<4, false><<<dim3(256, 1), 256, 0, stream>>>(
            attnob, wb_op + (size_t)l * 16384, out_proj_b + l * 128, z, zb,
            ln1_s + l * 128, ln1_bb + l * 128, 32768, 128, 128);
        for (int c = 0; c < nc; ++c) {
            mfma_gemm<2, true><<<dim3(CH / 128, 16), 256, 0, stream>>>(
                zb + (size_t)c * CH * 128, wb_l1 + (size_t)l * 262144, lin1_b + l * 2048,
                nullptr, ffb, nullptr, nullptr, CH, 2048, 128);
            // lin2 + residual + LN2 fused
            mfma_gemm<4, false><<<dim3(CH / 128, 1), 256, 0, stream>>>(
                ffb, wb_l2 + (size_t)l * 262144, lin2_b + l * 128,
                z + (size_t)c * CH * 128, zb + (size_t)c * CH * 128,
                ln2_s + l * 128, ln2_bb + l * 128, CH, 128, 2048);
        }
    }

    score_kernel<<<BB * SS / 64, 256, 0, stream>>>(z, score_w, score_b, tm, scores);
    pool_kernel<<<BB, 256, 0, stream>>>(z, scores, pooled);
    head_kernel<<<BB, 128, 0, stream>>>(pooled, reg_w, reg_b, bin_w, bin_b, window_id, out);
}

// Round 5
// 678.244 us; speedup vs baseline: 2.8747x; 1.0143x over previous
//
#include <hip/hip_runtime.h>

typedef __attribute__((ext_vector_type(8))) short short8;
typedef __attribute__((ext_vector_type(4))) float f32x4;
typedef unsigned short u16;

#define BB   128
#define SS   256
#define FIN  40
#define HH   64
#define DD   128
#define NHH  4
#define LL   2
#define NEGV (-1e9f)

__device__ __forceinline__ u16 f2b(float f) {
    unsigned u = __float_as_uint(f);
    return (u16)((u + 0x7FFFu + ((u >> 16) & 1u)) >> 16);
}
__device__ __forceinline__ float b2f(u16 u) {
    return __uint_as_float(((unsigned)u) << 16);
}

// ---------------------------------------------------------------- merged fp32 -> bf16 weight convert
__global__ __launch_bounds__(256) void cvt_all_kernel(const float* __restrict__ dm_w,
                                                      const float* __restrict__ ip_w,
                                                      const float* __restrict__ op_w,
                                                      const float* __restrict__ l1_w,
                                                      const float* __restrict__ l2_w,
                                                      u16* __restrict__ o_dm, u16* __restrict__ o_ip,
                                                      u16* __restrict__ o_op, u16* __restrict__ o_l1,
                                                      u16* __restrict__ o_l2) {
    int blk = blockIdx.x;
    const float* s; u16* d; int off;
    if      (blk < 4)   { s = dm_w; d = o_dm; off = blk; }
    else if (blk < 52)  { s = ip_w; d = o_ip; off = blk - 4; }
    else if (blk < 68)  { s = op_w; d = o_op; off = blk - 52; }
    else if (blk < 324) { s = l1_w; d = o_l1; off = blk - 68; }
    else                { s = l2_w; d = o_l2; off = blk - 324; }
    int i = (off * 256 + threadIdx.x) * 8;
    float4 a = *(const float4*)&s[i];
    float4 b = *(const float4*)&s[i + 4];
    short8 o;
    o[0] = (short)f2b(a.x); o[1] = (short)f2b(a.y); o[2] = (short)f2b(a.z); o[3] = (short)f2b(a.w);
    o[4] = (short)f2b(b.x); o[5] = (short)f2b(b.y); o[6] = (short)f2b(b.z); o[7] = (short)f2b(b.w);
    *(short8*)&d[i] = o;
}

// ---------------------------------------------------------------- time mask
__global__ __launch_bounds__(256) void tm_kernel(const float* __restrict__ mask,
                                                 float* __restrict__ tm) {
    int i = blockIdx.x * blockDim.x + threadIdx.x;
    if (i >= BB * SS) return;
    const float* m = mask + (size_t)i * FIN;
    float s = 0.f;
    for (int f = 0; f < FIN; ++f) s += m[f];
    tm[i] = (s > 0.f) ? 1.f : 0.f;
}

// ------------------------------------------------- xw = concat(x,mask,delta) @ W_ih^T + b_ih
#define XW_RPB 16
__global__ __launch_bounds__(192) void xw_kernel(const float* __restrict__ x,
                                                 const float* __restrict__ mask,
                                                 const float* __restrict__ delta,
                                                 const float* __restrict__ w_ih,
                                                 const float* __restrict__ b_ih,
                                                 float* __restrict__ xw) {
    __shared__ float inp[XW_RPB][120];
    __shared__ float wl[192][21];
    int row0 = blockIdx.x * XW_RPB;
    int tid  = threadIdx.x;

    for (int idx = tid; idx < XW_RPB * 120; idx += 192) {
        int r = idx / 120, k = idx % 120;
        int g = row0 + r;
        float v;
        if (k < 40)      v = x[(size_t)g * FIN + k];
        else if (k < 80) v = mask[(size_t)g * FIN + (k - 40)];
        else             v = delta[(size_t)g * FIN + (k - 80)];
        inp[r][k] = v;
    }

    float acc[XW_RPB];
#pragma unroll
    for (int r = 0; r < XW_RPB; ++r) acc[r] = 0.f;

    for (int kt = 0; kt < 6; ++kt) {
        __syncthreads();
        for (int idx = tid; idx < 192 * 20; idx += 192) {
            int r = idx / 20, k = idx % 20;
            wl[r][k] = w_ih[(size_t)r * 120 + kt * 20 + k];
        }
        __syncthreads();
#pragma unroll
        for (int kk = 0; kk < 20; ++kk) {
            float w = wl[tid][kk];
            int kg = kt * 20 + kk;
#pragma unroll
            for (int r = 0; r < XW_RPB; ++r) acc[r] += w * inp[r][kg];
        }
    }
    float bias = b_ih[tid];
    for (int r = 0; r < XW_RPB; ++r)
        xw[(size_t)(row0 + r) * 192 + tid] = acc[r] + bias;
}

// ---------------------------------------------------------------- GRU scan: 3 waves/batch-row
// thread j owns gate-row j (64 weights = 16 float4). IN-LOOP asm pin: the volatile asm
// redefines the weights every iteration, so the compiler cannot sink the loads back into
// the loop (the R2-R4 failure mode: loop-invariant loads rematerialized from L2 per step).
__global__ __launch_bounds__(192, 1) void gru_scan_kernel(const float* __restrict__ w_hh,
                                                          const float* __restrict__ b_hh,
                                                          const float* __restrict__ xw,
                                                          u16* __restrict__ hsb) {
    __shared__ float h[HH];
    __shared__ float gh[3 * HH];
    __shared__ float xs[3 * HH];
    int b = blockIdx.x, j = threadIdx.x;

    float4 w4[16];
    const float4* pw = (const float4*)(w_hh + (size_t)j * HH);
#pragma unroll
    for (int k = 0; k < 16; ++k) w4[k] = pw[k];

    float bh = b_hh[j];
    if (j < HH) h[j] = 0.f;
    const float* xwb = xw + (size_t)b * SS * 192;
    float xv = xwb[j];
    __syncthreads();

    for (int t = 0; t < SS; ++t) {
        // pin weights in VGPRs THIS iteration (no-op instruction-wise, blocks remat)
#pragma unroll
        for (int k = 0; k < 16; ++k)
            asm volatile("" : "+v"(w4[k].x), "+v"(w4[k].y), "+v"(w4[k].z), "+v"(w4[k].w));

        float px = xwb[(size_t)(t + 1 < SS ? t + 1 : t) * 192 + j];   // prefetch next step
        // 4 independent 16-FMA chains
        float a0 = bh, a1 = 0.f, a2 = 0.f, a3 = 0.f;
#pragma unroll
        for (int k = 0; k < 4; ++k) {
            float4 h0 = *(const float4*)&h[k * 16];
            float4 h1 = *(const float4*)&h[k * 16 + 4];
            float4 h2 = *(const float4*)&h[k * 16 + 8];
            float4 h3 = *(const float4*)&h[k * 16 + 12];
            float4 wa = w4[k * 4], wb = w4[k * 4 + 1], wc = w4[k * 4 + 2], wd = w4[k * 4 + 3];
            a0 += wa.x*h0.x + wa.y*h0.y + wa.z*h0.z + wa.w*h0.w;
            a1 += wb.x*h1.x + wb.y*h1.y + wb.z*h1.z + wb.w*h1.w;
            a2 += wc.x*h2.x + wc.y*h2.y + wc.z*h2.z + wc.w*h2.w;
            a3 += wd.x*h3.x + wd.y*h3.y + wd.z*h3.z + wd.w*h3.w;
        }
        gh[j] = (a0 + a1) + (a2 + a3);
        xs[j] = xv;
        __syncthreads();
        if (j < HH) {
            float r  = 1.f / (1.f + __expf(-(xs[j] + gh[j])));
            float zg = 1.f / (1.f + __expf(-(xs[64 + j] + gh[64 + j])));
            float nx = xs[128 + j] + r * gh[128 + j];
            float n  = 2.f / (1.f + __expf(-2.f * nx)) - 1.f;   // tanh
            float hj = (1.f - zg) * n + zg * h[j];
            h[j] = hj;
            hsb[((size_t)b * SS + t) * HH + j] = f2b(hj);
        }
        __syncthreads();
        xv = px;
    }
}

// ---------------------------------------------------------------- bf16 MFMA GEMM (m97 structure)
// MODE: 1=f32 C, 2=bf16 Cb, 3=both, 4=fused residual+LayerNorm (N must be 128, bn==0):
//       z_row = LN(z_old + acc + bias) * ln_s + ln_b  -> C (fp32, in/out) and Cb (bf16)
__device__ __forceinline__ void gl_lds16(const void* g, void* s) {
    __builtin_amdgcn_global_load_lds(
        (const __attribute__((address_space(1))) void*)g,
        (__attribute__((address_space(3))) void*)s, 16, 0, 0);
}

template <int MODE, bool RELU>
__global__ __launch_bounds__(256, 2) void mfma_gemm(const u16* __restrict__ A,
                                                    const u16* __restrict__ W,
                                                    const float* __restrict__ bias,
                                                    float* __restrict__ C,
                                                    u16* __restrict__ Cb,
                                                    const float* __restrict__ lns,
                                                    const float* __restrict__ lnb,
                                                    int M, int N, int K) {
    __shared__ __align__(16) u16 Al[128 * 32];
    __shared__ __align__(16) u16 Bl[128 * 32];
    __shared__ float lred[2][2][128];
    int bm = blockIdx.x, bn = blockIdx.y;
    int tid = threadIdx.x;
    int w = tid >> 6, lane = tid & 63;
    int wrow = (w >> 1) * 64, wcol = (w & 1) * 64;
    int fr = lane & 15, fk = (lane >> 4) * 8;
    int hi = lane >> 4;
    int srow = lane >> 2;
    int scol = (lane & 3) * 8;

    const u16* Ag = A + ((size_t)bm * 128) * K + scol;
    const u16* Wg = W + ((size_t)bn * 128) * K + scol;

    f32x4 acc[4][4];
#pragma unroll
    for (int i = 0; i < 4; ++i)
#pragma unroll
        for (int jj = 0; jj < 4; ++jj) acc[i][jj] = (f32x4){0.f, 0.f, 0.f, 0.f};

    for (int kt = 0; kt < K; kt += 32) {
        __syncthreads();
#pragma unroll
        for (int i = 0; i < 2; ++i) {
            int c = w + i * 4;
            int row = c * 16 + srow;
            gl_lds16(Ag + (size_t)row * K + kt, &Al[c * 512]);
            gl_lds16(Wg + (size_t)row * K + kt, &Bl[c * 512]);
        }
        __syncthreads();
        short8 a[4], bq[4];
#pragma unroll
        for (int m = 0; m < 4; ++m)
            a[m] = *(const short8*)&Al[(wrow + m * 16 + fr) * 32 + fk];
#pragma unroll
        for (int n = 0; n < 4; ++n)
            bq[n] = *(const short8*)&Bl[(wcol + n * 16 + fr) * 32 + fk];
#pragma unroll
        for (int m = 0; m < 4; ++m)
#pragma unroll
            for (int n = 0; n < 4; ++n)
                acc[m][n] = __builtin_amdgcn_mfma_f32_16x16x32_bf16(a[m], bq[n], acc[m][n], 0, 0, 0);
    }

    float bv[4];
#pragma unroll
    for (int n = 0; n < 4; ++n) bv[n] = bias[bn * 128 + wcol + n * 16 + fr];

    if (MODE == 4) {
        // ---- fused residual + LayerNorm (N==128, bn==0) ----
        float v[4][4][4];
#pragma unroll
        for (int m = 0; m < 4; ++m)
#pragma unroll
            for (int j = 0; j < 4; ++j) {
                int row = bm * 128 + wrow + m * 16 + hi * 4 + j;
#pragma unroll
                for (int n = 0; n < 4; ++n)
                    v[m][n][j] = acc[m][n][j] + bv[n] + C[(size_t)row * 128 + wcol + n * 16 + fr];
            }
#pragma unroll
        for (int m = 0; m < 4; ++m)
#pragma unroll
            for (int j = 0; j < 4; ++j) {
                float s = v[m][0][j] + v[m][1][j] + v[m][2][j] + v[m][3][j];
                float q = v[m][0][j]*v[m][0][j] + v[m][1][j]*v[m][1][j]
                        + v[m][2][j]*v[m][2][j] + v[m][3][j]*v[m][3][j];
#pragma unroll
                for (int off = 1; off <= 8; off <<= 1) {
                    s += __shfl_xor(s, off);
                    q += __shfl_xor(q, off);
                }
                if (fr == 0) {
                    int lrow = wrow + m * 16 + hi * 4 + j;
                    lred[0][w & 1][lrow] = s;
                    lred[1][w & 1][lrow] = q;
                }
            }
        __syncthreads();
        float sv[4], bb[4];
#pragma unroll
        for (int n = 0; n < 4; ++n) {
            sv[n] = lns[wcol + n * 16 + fr];
            bb[n] = lnb[wcol + n * 16 + fr];
        }
#pragma unroll
        for (int m = 0; m < 4; ++m)
#pragma unroll
            for (int j = 0; j < 4; ++j) {
                int lrow = wrow + m * 16 + hi * 4 + j;
                float mean = (lred[0][0][lrow] + lred[0][1][lrow]) * (1.f / 128.f);
                float msq  = (lred[1][0][lrow] + lred[1][1][lrow]) * (1.f / 128.f);
                float rstd = rsqrtf(msq - mean * mean + 1e-5f);
                int row = bm * 128 + lrow;
#pragma unroll
                for (int n = 0; n < 4; ++n) {
                    int col = wcol + n * 16 + fr;
                    float o = (v[m][n][j] - mean) * rstd * sv[n] + bb[n];
                    C[(size_t)row * 128 + col] = o;
                    Cb[(size_t)row * 128 + col] = f2b(o);
                }
            }
    } else {
#pragma unroll
        for (int m = 0; m < 4; ++m) {
#pragma unroll
            for (int j = 0; j < 4; ++j) {
                int row = bm * 128 + wrow + m * 16 + hi * 4 + j;
#pragma unroll
                for (int n = 0; n < 4; ++n) {
                    int col = bn * 128 + wcol + n * 16 + fr;
                    float vv = acc[m][n][j] + bv[n];
                    if (RELU) vv = fmaxf(vv, 0.f);
                    if (MODE & 1) C[(size_t)row * N + col] = vv;
                    if (MODE & 2) Cb[(size_t)row * N + col] = f2b(vv);
                }
            }
        }
    }
}

// ---------------------------------------------------------------- attention (bf16 qkv in, bf16 out)
__global__ __launch_bounds__(256) void attn_kernel(const u16* __restrict__ qkv,
                                                   const float* __restrict__ tm,
                                                   u16* __restrict__ attno) {
    int bh = blockIdx.x;
    int b = bh / NHH, hd = bh % NHH;
    int s = threadIdx.x;

    __shared__ float Kt[64][32];
    __shared__ float Vt[64][32];
    __shared__ float tms[64];

    float q[32];
    const u16* qrow = qkv + ((size_t)b * SS + s) * 384 + hd * 32;
#pragma unroll
    for (int j = 0; j < 32; j += 8) {
        short8 v = *(const short8*)&qrow[j];
#pragma unroll
        for (int jj = 0; jj < 8; ++jj) q[j + jj] = b2f((u16)v[jj]);
    }
    const float scale = 0.17677669529663687f;
    float denom = 0.f;
    float o[32];
#pragma unroll
    for (int j = 0; j < 32; ++j) o[j] = 0.f;

    for (int kt = 0; kt < SS; kt += 64) {
        __syncthreads();
        {
            int r = s >> 2, c = (s & 3) * 8;
            const u16* kb = qkv + ((size_t)b * SS + kt + r) * 384 + 128 + hd * 32 + c;
            const u16* vb = qkv + ((size_t)b * SS + kt + r) * 384 + 256 + hd * 32 + c;
            short8 kv = *(const short8*)kb;
            short8 vv = *(const short8*)vb;
#pragma unroll
            for (int jj = 0; jj < 8; ++jj) {
                Kt[r][c + jj] = b2f((u16)kv[jj]);
                Vt[r][c + jj] = b2f((u16)vv[jj]);
            }
        }
        if (s < 64) tms[s] = tm[b * SS + kt + s];
        __syncthreads();
        for (int k = 0; k < 64; ++k) {
            float acc = 0.f;
#pragma unroll
            for (int j = 0; j < 32; ++j) acc += q[j] * Kt[k][j];
            float sc = acc * scale + (tms[k] > 0.f ? 0.f : NEGV);
            float e = __expf(sc);
            denom += e;
#pragma unroll
            for (int j = 0; j < 32; ++j) o[j] += e * Vt[k][j];
        }
    }
    float inv = 1.f / denom;
    u16* orow = attno + ((size_t)b * SS + s) * DD + hd * 32;
#pragma unroll
    for (int j = 0; j < 32; j += 8) {
        short8 ov;
#pragma unroll
        for (int jj = 0; jj < 8; ++jj) ov[jj] = (short)f2b(o[j + jj] * inv);
        *(short8*)&orow[j] = ov;
    }
}

// ---------------------------------------------------------------- score = z @ score_w^T + b (masked)
__global__ __launch_bounds__(256) void score_kernel(const float* __restrict__ z,
                                                    const float* __restrict__ score_w,
                                                    const float* __restrict__ score_b,
                                                    const float* __restrict__ tm,
                                                    float* __restrict__ scores) {
    int row = blockIdx.x * 64 + (threadIdx.x >> 2);
    int c = threadIdx.x & 3;
    const float* zr = z + (size_t)row * DD + c * 32;
    const float* wr = score_w + c * 32;
    float acc = 0.f;
#pragma unroll
    for (int j = 0; j < 32; j += 4) {
        float4 a = *(const float4*)(zr + j), w = *(const float4*)(wr + j);
        acc += a.x * w.x + a.y * w.y + a.z * w.z + a.w * w.w;
    }
    acc += __shfl_xor(acc, 1);
    acc += __shfl_xor(acc, 2);
    if (c == 0) {
        float sc = acc + score_b[0];
        scores[row] = (tm[row] > 0.f) ? sc : NEGV;
    }
}

// ---------------------------------------------------------------- softmax over S + weighted pool
__global__ __launch_bounds__(256) void pool_kernel(const float* __restrict__ z,
                                                   const float* __restrict__ scores,
                                                   float* __restrict__ pooled) {
    int b = blockIdx.x;
    int tid = threadIdx.x;
    __shared__ float al[SS];
    __shared__ float red[8];
    __shared__ float pp[2][128];

    float sc = scores[b * SS + tid];
    float m = sc;
#pragma unroll
    for (int off = 32; off; off >>= 1) m = fmaxf(m, __shfl_xor(m, off));
    if ((tid & 63) == 0) red[tid >> 6] = m;
    __syncthreads();
    m = fmaxf(fmaxf(red[0], red[1]), fmaxf(red[2], red[3]));
    float e = __expf(sc - m);
    float ssum = e;
#pragma unroll
    for (int off = 32; off; off >>= 1) ssum += __shfl_xor(ssum, off);
    if ((tid & 63) == 0) red[4 + (tid >> 6)] = ssum;
    __syncthreads();
    ssum = red[4] + red[5] + red[6] + red[7];
    al[tid] = e / ssum;
    __syncthreads();

    int d = tid & 127, half = tid >> 7;
    float acc = 0.f;
    for (int t = half; t < SS; t += 2) acc += al[t] * z[((size_t)b * SS + t) * DD + d];
    pp[half][d] = acc;
    __syncthreads();
    if (tid < 128) pooled[b * 128 + tid] = pp[0][tid] + pp[1][tid];
}

// ---------------------------------------------------------------- routed heads
__global__ __launch_bounds__(128) void head_kernel(const float* __restrict__ pooled,
                                                   const float* __restrict__ reg_w,
                                                   const float* __restrict__ reg_b,
                                                   const float* __restrict__ bin_w,
                                                   const float* __restrict__ bin_b,
                                                   const int* __restrict__ wid,
                                                   float* __restrict__ out) {
    int b = blockIdx.x, tid = threadIdx.x;
    __shared__ float p[128];
    p[tid] = pooled[b * 128 + tid];
    __syncthreads();
    if (tid < 9) {
        int w = wid[b];
        const float* wrow;
        float bias;
        if (tid < 8) { wrow = reg_w + ((size_t)w * 8 + tid) * 128; bias = reg_b[w * 8 + tid]; }
        else         { wrow = bin_w + (size_t)w * 128;             bias = bin_b[w]; }
        float acc = bias;
        for (int k = 0; k < 128; ++k) acc += wrow[k] * p[k];
        if (tid < 8) out[b * 8 + tid] = acc;
        else         out[1024 + b] = acc;
    }
}

// ================================================================ host
extern "C" void kernel_launch(void* const* d_in, const int* in_sizes, int n_in,
                              void* d_out, int out_size, void* d_ws, size_t ws_size,
                              hipStream_t stream) {
    const float* x         = (const float*)d_in[0];
    const float* mask      = (const float*)d_in[1];
    const float* delta     = (const float*)d_in[2];
    const float* gru_w_ih  = (const float*)d_in[3];
    const float* gru_w_hh  = (const float*)d_in[4];
    const float* gru_b_ih  = (const float*)d_in[5];
    const float* gru_b_hh  = (const float*)d_in[6];
    const float* dm_w      = (const float*)d_in[7];
    const float* dm_b      = (const float*)d_in[8];
    const float* in_proj_w = (const float*)d_in[9];
    const float* in_proj_b = (const float*)d_in[10];
    const float* out_proj_w= (const float*)d_in[11];
    const float* out_proj_b= (const float*)d_in[12];
    const float* lin1_w    = (const float*)d_in[13];
    const float* lin1_b    = (const float*)d_in[14];
    const float* lin2_w    = (const float*)d_in[15];
    const float* lin2_b    = (const float*)d_in[16];
    const float* ln1_s     = (const float*)d_in[17];
    const float* ln1_bb    = (const float*)d_in[18];
    const float* ln2_s     = (const float*)d_in[19];
    const float* ln2_bb    = (const float*)d_in[20];
    const float* score_w   = (const float*)d_in[21];
    const float* score_b   = (const float*)d_in[22];
    const float* reg_w     = (const float*)d_in[23];
    const float* reg_b     = (const float*)d_in[24];
    const float* bin_w     = (const float*)d_in[25];
    const float* bin_b     = (const float*)d_in[26];
    const int*   window_id = (const int*)d_in[27];
    float* out = (float*)d_out;

    char* w8 = (char*)d_ws;
    float* z      = (float*)(w8 + 0);            // 16,777,216
    u16*   zb     = (u16*)  (w8 + 16777216);     //  8,388,608
    u16*   hsb    = (u16*)  (w8 + 25165824);     //  4,194,304
    u16*   wb_dm  = (u16*)  (w8 + 29360128);     //     16,384
    u16*   wb_ip  = (u16*)  (w8 + 29376512);     //    196,608
    u16*   wb_op  = (u16*)  (w8 + 29573120);     //     65,536
    u16*   wb_l1  = (u16*)  (w8 + 29638656);     //  1,048,576
    u16*   wb_l2  = (u16*)  (w8 + 30687232);     //  1,048,576
    float* tm     = (float*)(w8 + 31735808);     //    131,072
    float* scores = (float*)(w8 + 31866880);     //    131,072
    float* pooled = (float*)(w8 + 31997952);     //     65,536
    float* xw     = (float*)(w8 + 32063488);     // 25,165,824 (GRU: xw fp32 | later: qkvb bf16)
    u16*   qkvb   = (u16*)  (w8 + 32063488);
    u16*   ffb    = (u16*)  (w8 + 57229312);     // CH*2048*2 ; attnob aliased at base
    u16*   attnob = ffb;

    int CH = 4096;
    if      (ws_size >= 57229312ull + 134217728ull) CH = 32768;
    else if (ws_size >= 57229312ull +  33554432ull) CH = 8192;
    int nc = 32768 / CH;

    cvt_all_kernel<<<580, 256, 0, stream>>>(dm_w, in_proj_w, out_proj_w, lin1_w, lin2_w,
                                            wb_dm, wb_ip, wb_op, wb_l1, wb_l2);

    tm_kernel<<<(BB * SS + 255) / 256, 256, 0, stream>>>(mask, tm);
    xw_kernel<<<BB * SS / XW_RPB, 192, 0, stream>>>(x, mask, delta, gru_w_ih, gru_b_ih, xw);
    gru_scan_kernel<<<BB, 192, 0, stream>>>(gru_w_hh, gru_b_hh, xw, hsb);

    mfma_gemm<3, false><<<dim3(256, 1), 256, 0, stream>>>(
        hsb, wb_dm, dm_b, z, zb, nullptr, nullptr, 32768, 128, 64);

    for (int l = 0; l < LL; ++l) {
        mfma_gemm<2, false><<<dim3(256, 3), 256, 0, stream>>>(
            zb, wb_ip + (size_t)l * 49152, in_proj_b + l * 384, nullptr, qkvb,
            nullptr, nullptr, 32768, 384, 128);
        attn_kernel<<<BB * NHH, 256, 0, stream>>>(qkvb, tm, attnob);
        // out_proj + residual + LN1 fused
        mfma_gemm<4, false><<<dim3(256, 1), 256, 0, stream>>>(
            attnob, wb_op + (size_t)l * 16384, out_proj_b + l * 128, z, zb,
            ln1_s + l * 128, ln1_bb + l * 128, 32768, 128, 128);
        for (int c = 0; c < nc; ++c) {
            mfma_gemm<2, true><<<dim3(CH / 128, 16), 256, 0, stream>>>(
                zb + (size_t)c * CH * 128, wb_l1 + (size_t)l * 262144, lin1_b + l * 2048,
                nullptr, ffb, nullptr, nullptr, CH, 2048, 128);
            // lin2 + residual + LN2 fused
            mfma_gemm<4, false><<<dim3(CH / 128, 1), 256, 0, stream>>>(
                ffb, wb_l2 + (size_t)l * 262144, lin2_b + l * 128,
                z + (size_t)c * CH * 128, zb + (size_t)c * CH * 128,
                ln2_s + l * 128, ln2_bb + l * 128, CH, 128, 2048);
        }
    }

    score_kernel<<<BB * SS / 64, 256, 0, stream>>>(z, score_w, score_b, tm, scores);
    pool_kernel<<<BB, 256, 0, stream>>>(z, scores, pooled);
    head_kernel<<<BB, 128, 0, stream>>>(pooled, reg_w, reg_b, bin_w, bin_b, window_id, out);
}